// Round 2
// baseline (420.467 us; speedup 1.0000x reference)
//
#include <hip/hip_runtime.h>
#include <hip/hip_bf16.h>
#include <math.h>

#define B_ 8192
#define L_ 512
#define BL_ (B_ * L_)
#define KT_ 1536

__device__ __forceinline__ float gelu_f(float v) {
    return 0.5f * v * (1.0f + erff(v * 0.70710678118654752f));
}
__device__ __forceinline__ float bf2f(unsigned short u) {
    return __uint_as_float(((unsigned int)u) << 16);
}
__device__ __forceinline__ unsigned short f2bf(float f) {
    unsigned int x = __float_as_uint(f);
    x += 0x7fffu + ((x >> 16) & 1u);   // RNE
    return (unsigned short)(x >> 16);
}

// conv1 (1->3ch, k=3, pad 1) + exact GELU -> h1 bf16 [b][c][i]
__global__ __launch_bounds__(256) void k_conv1(const float* __restrict__ x,
        const float* __restrict__ w, const float* __restrict__ bias,
        unsigned short* __restrict__ h1) {
    int idx = blockIdx.x * 256 + threadIdx.x;      // over B*L exactly
    int b = idx >> 9, i = idx & 511;
    const float* xr = x + ((long)b << 9);
    float xm = i ? xr[i - 1] : 0.f;
    float x0 = xr[i];
    float xp = (i != 511) ? xr[i + 1] : 0.f;
    unsigned short* hb = h1 + (long)b * KT_ + i;
#pragma unroll
    for (int c = 0; c < 3; ++c) {
        float v = w[c * 3] * xm + w[c * 3 + 1] * x0 + w[c * 3 + 2] * xp + bias[c];
        hb[(long)c << 9] = f2bf(gelu_f(v));
    }
}

// per-row LayerNorm stats (mu, rstd), one wave per row
__global__ __launch_bounds__(256) void k_stats(const float* __restrict__ x,
                                               float2* __restrict__ st) {
    const int gid = blockIdx.x * 256 + threadIdx.x;
    const int row = gid >> 6;
    const int lane = gid & 63;
    const float* xr = x + ((long)row << 9);
    float s = 0.f, ss = 0.f;
#pragma unroll
    for (int j = 0; j < 8; ++j) {
        float v = xr[lane + (j << 6)];
        s += v; ss = fmaf(v, v, ss);
    }
#pragma unroll
    for (int off = 32; off > 0; off >>= 1) {
        s += __shfl_xor(s, off);
        ss += __shfl_xor(ss, off);
    }
    if (lane == 0) {
        float muv = s * (1.f / 512.f);
        float var = ss * (1.f / 512.f) - muv * muv;
        st[row] = make_float2(muv, rsqrtf(var + 1e-5f));
    }
}

// C[M,N] = A[M,K] * W[N,K]^T + sbias*bias[N]  (NT GEMM), 64x64x16 tiles, 4x4/thread
// AMODE: 0 = A is bf16 (stride KD); 1 = LayerNorm(x) on the fly (x fp32 + stats + g,b)
// WMODE: 0 = Weff from conv3_w on the fly;  1 = plain fp32 W[N,K]
// EMODE: 0 = fp32 store; 1 = GELU -> bf16 store; 2 = +xres residual -> fp32 store
template<int AMODE, int WMODE, int EMODE, int KD>
__global__ __launch_bounds__(256) void k_gemm(
        const void* __restrict__ Ap, const void* __restrict__ Wp,
        const float* __restrict__ bias, float sbias,
        const float2* __restrict__ st, const float* __restrict__ lg,
        const float* __restrict__ lb, const float* __restrict__ xres,
        void* __restrict__ Cp) {
    __shared__ float As[16][64];
    __shared__ float Ws[16][64];
    const int tid = threadIdx.x;
    const int m0 = blockIdx.x << 6;
    const int n0 = blockIdx.y << 6;
    const int lm = tid >> 2;          // 0..63
    const int lk = (tid & 3) << 2;    // 0,4,8,12
    const int tx = tid & 15, ty = tid >> 4;
    float acc[4][4] = {};
    float mu = 0.f, rs = 0.f;
    if (AMODE == 1) { float2 s = st[m0 + lm]; mu = s.x; rs = s.y; }
    for (int k0 = 0; k0 < KD; k0 += 16) {
        float av[4], wv[4];
        if (AMODE == 1) {
            const float* xr = (const float*)Ap + (long)(m0 + lm) * 512 + k0 + lk;
            float4 xv = *(const float4*)xr;
            float4 gv = *(const float4*)(lg + k0 + lk);
            float4 bv = *(const float4*)(lb + k0 + lk);
            av[0] = fmaf((xv.x - mu) * rs, gv.x, bv.x);
            av[1] = fmaf((xv.y - mu) * rs, gv.y, bv.y);
            av[2] = fmaf((xv.z - mu) * rs, gv.z, bv.z);
            av[3] = fmaf((xv.w - mu) * rs, gv.w, bv.w);
        } else {
            const unsigned short* hr = (const unsigned short*)Ap + (long)(m0 + lm) * KD + k0 + lk;
            ushort4 u = *(const ushort4*)hr;
            av[0] = bf2f(u.x); av[1] = bf2f(u.y); av[2] = bf2f(u.z); av[3] = bf2f(u.w);
        }
        if (WMODE == 0) {
            const int c = k0 >> 9;
            const int i0 = (k0 & 511) + lk;
            const float* wr = (const float*)Wp + (long)(n0 + lm) * KT_ + (long)i0 * 3;
            float4 f0 = *(const float4*)wr;
            float4 f1 = *(const float4*)(wr + 4);
            float4 f2 = *(const float4*)(wr + 8);
            const float a0 = (c == 0) ? 0.25f : (c == 1 ? 0.125f : 0.f);
            const float a1 = (c == 0) ? 0.5f  : (c == 1 ? 0.25f  : 0.125f);
            const float a2 = (c == 0) ? 0.f   : (c == 1 ? 0.5f   : 0.25f);
            wv[0] = a0 * f0.x + a1 * f0.y + a2 * f0.z;
            wv[1] = a0 * f0.w + a1 * f1.x + a2 * f1.y;
            wv[2] = a0 * f1.z + a1 * f1.w + a2 * f2.x;
            wv[3] = a0 * f2.y + a1 * f2.z + a2 * f2.w;
        } else {
            const float* wr = (const float*)Wp + (long)(n0 + lm) * KD + k0 + lk;
            float4 w4 = *(const float4*)wr;
            wv[0] = w4.x; wv[1] = w4.y; wv[2] = w4.z; wv[3] = w4.w;
        }
        __syncthreads();
#pragma unroll
        for (int j = 0; j < 4; ++j) As[lk + j][lm] = av[j];
#pragma unroll
        for (int j = 0; j < 4; ++j) Ws[lk + j][lm] = wv[j];
        __syncthreads();
#pragma unroll
        for (int kk = 0; kk < 16; ++kk) {
            float4 a = *(const float4*)(&As[kk][ty << 2]);
            float4 w = *(const float4*)(&Ws[kk][tx << 2]);
            float ar[4] = {a.x, a.y, a.z, a.w};
            float wr4[4] = {w.x, w.y, w.z, w.w};
#pragma unroll
            for (int ii = 0; ii < 4; ++ii)
#pragma unroll
                for (int jj = 0; jj < 4; ++jj)
                    acc[ii][jj] = fmaf(ar[ii], wr4[jj], acc[ii][jj]);
        }
    }
    const int cn = n0 + (tx << 2);
    float bz[4];
#pragma unroll
    for (int j = 0; j < 4; ++j) bz[j] = sbias * bias[cn + j];
#pragma unroll
    for (int ii = 0; ii < 4; ++ii) {
        const long m = m0 + (ty << 2) + ii;
        float c0 = acc[ii][0] + bz[0], c1 = acc[ii][1] + bz[1];
        float c2 = acc[ii][2] + bz[2], c3 = acc[ii][3] + bz[3];
        if (EMODE == 0) {
            float4 o; o.x = c0; o.y = c1; o.z = c2; o.w = c3;
            *(float4*)((float*)Cp + m * 512 + cn) = o;
        } else if (EMODE == 1) {
            ushort4 o;
            o.x = f2bf(gelu_f(c0)); o.y = f2bf(gelu_f(c1));
            o.z = f2bf(gelu_f(c2)); o.w = f2bf(gelu_f(c3));
            *(ushort4*)((unsigned short*)Cp + m * 512 + cn) = o;
        } else {
            const float4 r = *(const float4*)(xres + m * 512 + cn);
            float4 o; o.x = c0 + r.x; o.y = c1 + r.y; o.z = c2 + r.z; o.w = c3 + r.w;
            *(float4*)((float*)Cp + m * 512 + cn) = o;
        }
    }
}

// season: 512-pt real DFT bins 1..255 via Cooley-Tukey 16x32 (stage1 fp32,
// stage2 + |X|^2 in double), top-5 (tie -> lower index), cosine synthesis.
__global__ __launch_bounds__(256) void k_season(const float* __restrict__ x,
                                                float* __restrict__ out1) {
    __shared__ float xs[512];
    __shared__ float2 tab[512];     // (cos,sin)(2*pi*i/512) fp32
    __shared__ float2 tab32[32];    // (cos,sin)(2*pi*i/32)
    __shared__ double2 tabd[512];   // double twiddles
    __shared__ float2 Ys[512];      // stage-1 outputs [t0][r]
    __shared__ double wmag[4];
    __shared__ int widx[4];
    __shared__ float4 sel[5];

    const int tid = threadIdx.x;
    const long b = blockIdx.x;
    const float* xr = x + (b << 9);
    xs[tid] = xr[tid];
    xs[tid + 256] = xr[tid + 256];
    for (int i = tid; i < 512; i += 256) {
        double sv, cv;
        sincos((double)i * (3.14159265358979323846 / 256.0), &sv, &cv);
        tabd[i] = make_double2(cv, sv);
        tab[i] = make_float2((float)cv, (float)sv);
        if ((i & 15) == 0) tab32[i >> 4] = make_float2((float)cv, (float)sv);
    }
    __syncthreads();

    // stage 1: Y[t0][r] = sum_{t1<32} x[16*t1+t0] * e^{-2pi i r t1/32}
    const int r = tid & 31;
    const int t0a = tid >> 5;       // 0..7 (also handles t0a+8)
    float re0 = 0.f, im0 = 0.f, re1 = 0.f, im1 = 0.f;
    for (int t1 = 0; t1 < 32; ++t1) {
        float2 w = tab32[(r * t1) & 31];
        float xa = xs[(t1 << 4) + t0a];
        float xb = xs[(t1 << 4) + t0a + 8];
        re0 = fmaf(xa, w.x, re0); im0 = fmaf(xa, w.y, im0);
        re1 = fmaf(xb, w.x, re1); im1 = fmaf(xb, w.y, im1);
    }
    Ys[(t0a << 5) + r] = make_float2(re0, -im0);
    Ys[((t0a + 8) << 5) + r] = make_float2(re1, -im1);
    __syncthreads();

    // stage 2 (double): X_k = sum_{t0<16} e^{-2pi i k t0/512} * Y[t0][k&31]
    double xre = 0.0, xim = 0.0, mag = -1.0;
    const int k = tid + 1;
    if (tid < 255) {
        const int rr = k & 31;
        for (int t0 = 0; t0 < 16; ++t0) {
            float2 y = Ys[(t0 << 5) + rr];
            double2 w = tabd[(k * t0) & 511];
            xre += (double)y.x * w.x + (double)y.y * w.y;
            xim += (double)y.y * w.x - (double)y.x * w.y;
        }
        mag = xre * xre + xim * xim;
    }

    // top-5 by magnitude, tie -> lower bin index (matches lax.top_k)
    double mymag = mag; int myk = k;
    for (int rnd = 0; rnd < 5; ++rnd) {
        double m = mymag; int i = myk;
#pragma unroll
        for (int off = 32; off > 0; off >>= 1) {
            double om = __shfl_xor(m, off);
            int oi = __shfl_xor(i, off);
            if (om > m || (om == m && oi < i)) { m = om; i = oi; }
        }
        if ((tid & 63) == 0) { wmag[tid >> 6] = m; widx[tid >> 6] = i; }
        __syncthreads();
        double gm = -2.0; int gi = 1 << 20;
#pragma unroll
        for (int w = 0; w < 4; ++w) {
            double pm = wmag[w]; int pi = widx[w];
            if (pm > gm || (pm == gm && pi < gi)) { gm = pm; gi = pi; }
        }
        if (tid < 255 && myk == gi) {
            sel[rnd] = make_float4((float)myk, (float)xre, (float)xim, 0.f);
            mymag = -1.0;
        }
        __syncthreads();
    }

    // synthesis: season[t] = 2 * sum_j (Re_j cos(2pi k_j t/512) - Im_j sin(...))
#pragma unroll
    for (int half = 0; half < 2; ++half) {
        int t = tid + (half << 8);
        float acc = 0.f;
#pragma unroll
        for (int j = 0; j < 5; ++j) {
            float4 sj = sel[j];
            int kj = (int)sj.x;
            float2 w = tab[(kj * t) & 511];
            acc += sj.y * w.x - sj.z * w.y;
        }
        out1[(b << 9) + t] = 2.f * acc;
    }
}

__global__ __launch_bounds__(256) void k_zero(float4* __restrict__ p) {
    p[(long)blockIdx.x * 256 + threadIdx.x] = make_float4(0.f, 0.f, 0.f, 0.f);
}

extern "C" void kernel_launch(void* const* d_in, const int* in_sizes, int n_in,
                              void* d_out, int out_size, void* d_ws, size_t ws_size,
                              hipStream_t stream) {
    const float* x   = (const float*)d_in[0];
    const float* c1w = (const float*)d_in[1];
    const float* c1b = (const float*)d_in[2];
    const float* c3w = (const float*)d_in[3];
    const float* c3b = (const float*)d_in[4];
    const float* w1  = (const float*)d_in[5];
    const float* b1  = (const float*)d_in[6];
    const float* w2  = (const float*)d_in[7];
    const float* b2  = (const float*)d_in[8];
    const float* lg  = (const float*)d_in[9];
    const float* lb  = (const float*)d_in[10];

    float* out  = (float*)d_out;
    float* out1 = out + (long)BL_;          // season
    float* out2 = out + 2L * BL_;           // trend
    float* out3 = out + 3L * BL_;           // e (== mean)

    // scratch carved from d_out regions (lifetimes ordered below):
    unsigned short* h1 = (unsigned short*)d_out;                    // bf16, 24 MB in [out0|out1)
    float2* st = (float2*)d_out;                                    // 64 KB in out0 (after G1)
    unsigned short* m1 = (unsigned short*)((char*)d_out + 65536);   // bf16, 8 MB in out0

    // 1) conv1+GELU -> h1
    k_conv1<<<BL_ / 256, 256, 0, stream>>>(x, c1w, c1b, h1);
    // 2) trend GEMM (Weff from conv3_w on the fly) -> out2
    k_gemm<0, 0, 0, KT_><<<dim3(128, 8), 256, 0, stream>>>(
        h1, c3w, c3b, 0.875f, nullptr, nullptr, nullptr, nullptr, out2);
    // 3) season -> out1 (h1 upper region now dead)
    k_season<<<B_, 256, 0, stream>>>(x, out1);
    // 4) LN stats -> st (out0 region, h1 dead)
    k_stats<<<B_ * 64 / 256, 256, 0, stream>>>(x, st);
    // 5) MLP GEMM1: LN(x) @ w1^T + b1, GELU -> m1 (bf16)
    k_gemm<1, 1, 1, 512><<<dim3(128, 8), 256, 0, stream>>>(
        x, w1, b1, 1.0f, st, lg, lb, nullptr, m1);
    // 6) MLP GEMM2: m1 @ w2^T + b2 + x -> out3
    k_gemm<0, 1, 2, 512><<<dim3(128, 8), 256, 0, stream>>>(
        m1, w2, b2, 1.0f, nullptr, nullptr, nullptr, x, out3);
    // 7) out0 = 0 exactly (e - mean over size-1 axis)
    k_zero<<<4096, 256, 0, stream>>>((float4*)d_out);
}

// Round 4
// 157.678 us; speedup vs baseline: 2.6666x; 2.6666x over previous
//
#include <hip/hip_runtime.h>
#include <hip/hip_bf16.h>
#include <math.h>

#define B_ 8192
#define L_ 512
#define BL_ (B_ * L_)
#define KT_ 1536

using bf16x8 = __attribute__((ext_vector_type(8))) short;
using f32x4  = __attribute__((ext_vector_type(4))) float;

__device__ __forceinline__ float gelu_f(float v) {
    return 0.5f * v * (1.0f + erff(v * 0.70710678118654752f));
}
__device__ __forceinline__ float bf2f(unsigned short u) {
    return __uint_as_float(((unsigned int)u) << 16);
}
__device__ __forceinline__ unsigned short f2bf(float f) {
    unsigned int x = __float_as_uint(f);
    x += 0x7fffu + ((x >> 16) & 1u);   // RNE
    return (unsigned short)(x >> 16);
}
__device__ __forceinline__ void gload16(const void* g, void* l) {
    __builtin_amdgcn_global_load_lds(
        (const __attribute__((address_space(1))) unsigned int*)g,
        (__attribute__((address_space(3))) unsigned int*)l, 16, 0, 0);
}

// conv1 (1->3ch, k=3, pad 1) + exact GELU -> h1 bf16 [b][c][i]
__global__ __launch_bounds__(256) void k_conv1(const float* __restrict__ x,
        const float* __restrict__ w, const float* __restrict__ bias,
        unsigned short* __restrict__ h1) {
    int idx = blockIdx.x * 256 + threadIdx.x;
    int b = idx >> 9, i = idx & 511;
    const float* xr = x + ((long)b << 9);
    float xm = i ? xr[i - 1] : 0.f;
    float x0 = xr[i];
    float xp = (i != 511) ? xr[i + 1] : 0.f;
    unsigned short* hb = h1 + (long)b * KT_ + i;
#pragma unroll
    for (int c = 0; c < 3; ++c) {
        float v = w[c * 3] * xm + w[c * 3 + 1] * x0 + w[c * 3 + 2] * xp + bias[c];
        hb[(long)c << 9] = f2bf(gelu_f(v));
    }
}

// weight prep: Weff bf16 [512][1536] (collapsed conv3+poly), w1/w2 -> bf16 [N][K]
__global__ __launch_bounds__(256) void k_prep(const float* __restrict__ c3w,
        const float* __restrict__ w1, const float* __restrict__ w2,
        unsigned short* __restrict__ weff, unsigned short* __restrict__ w1b,
        unsigned short* __restrict__ w2b) {
    int idx = blockIdx.x * 256 + threadIdx.x;      // 512*512
    int o = idx >> 9, i = idx & 511;
    const float* t = c3w + (size_t)idx * 3;
    float t0 = t[0], t1 = t[1], t2 = t[2];
    size_t base = (size_t)o * KT_ + i;
    weff[base]        = f2bf(0.25f * t0 + 0.5f * t1);
    weff[base + 512]  = f2bf(0.125f * t0 + 0.25f * t1 + 0.5f * t2);
    weff[base + 1024] = f2bf(0.125f * t1 + 0.25f * t2);
    w1b[idx] = f2bf(w1[idx]);
    w2b[idx] = f2bf(w2[idx]);
}

// fused LayerNorm -> bf16 [row][512]; one wave per row
__global__ __launch_bounds__(256) void k_ln(const float* __restrict__ x,
        const float* __restrict__ g, const float* __restrict__ bb,
        unsigned short* __restrict__ lnx) {
    const int gid = blockIdx.x * 256 + threadIdx.x;
    const int row = gid >> 6, lane = gid & 63;
    const float* xr = x + ((size_t)row << 9);
    float4 v0 = *(const float4*)(xr + lane * 8);
    float4 v1 = *(const float4*)(xr + lane * 8 + 4);
    float s = v0.x + v0.y + v0.z + v0.w + v1.x + v1.y + v1.z + v1.w;
    float ss = v0.x*v0.x + v0.y*v0.y + v0.z*v0.z + v0.w*v0.w
             + v1.x*v1.x + v1.y*v1.y + v1.z*v1.z + v1.w*v1.w;
#pragma unroll
    for (int off = 32; off > 0; off >>= 1) {
        s += __shfl_xor(s, off);
        ss += __shfl_xor(ss, off);
    }
    float mu = s * (1.f / 512.f);
    float var = ss * (1.f / 512.f) - mu * mu;
    float rs = rsqrtf(var + 1e-5f);
    float4 g0 = *(const float4*)(g + lane * 8);
    float4 g1 = *(const float4*)(g + lane * 8 + 4);
    float4 b0 = *(const float4*)(bb + lane * 8);
    float4 b1 = *(const float4*)(bb + lane * 8 + 4);
    unsigned short o[8];
    o[0] = f2bf(fmaf((v0.x - mu) * rs, g0.x, b0.x));
    o[1] = f2bf(fmaf((v0.y - mu) * rs, g0.y, b0.y));
    o[2] = f2bf(fmaf((v0.z - mu) * rs, g0.z, b0.z));
    o[3] = f2bf(fmaf((v0.w - mu) * rs, g0.w, b0.w));
    o[4] = f2bf(fmaf((v1.x - mu) * rs, g1.x, b1.x));
    o[5] = f2bf(fmaf((v1.y - mu) * rs, g1.y, b1.y));
    o[6] = f2bf(fmaf((v1.z - mu) * rs, g1.z, b1.z));
    o[7] = f2bf(fmaf((v1.w - mu) * rs, g1.w, b1.w));
    ushort4* dst = (ushort4*)(lnx + ((size_t)row << 9) + lane * 8);
    dst[0] = make_ushort4(o[0], o[1], o[2], o[3]);
    dst[1] = make_ushort4(o[4], o[5], o[6], o[7]);
}

// MFMA GEMM: C[M,N] = A[M,K](bf16) * W[N,K](bf16)^T + sbias*bias
// BM=128 BN=64 BK=32, 256 thr = 4 waves, wave tile 64x32 (4x2 frags 16x16x32)
// LDS XOR-swizzle: phys slot = logical slot ^ ((row ^ row>>2)&3); inverse
// applied on the global source of global_load_lds (dest stays linear).
// EMODE: 0 fp32 store; 1 GELU->bf16 store; 2 +xres fp32 store
template<int EMODE, int KD>
__global__ __launch_bounds__(256) void k_mgemm(
        const unsigned short* __restrict__ A, const unsigned short* __restrict__ W,
        const float* __restrict__ bias, float sbias,
        const float* __restrict__ xres, void* __restrict__ Cp) {
    __shared__ short As[128][32];
    __shared__ short Bs[64][32];
    const int tid = threadIdx.x;
    const int lane = tid & 63;
    const int wid = tid >> 6;
    const int m0 = blockIdx.x << 7;
    const int n0 = blockIdx.y << 6;
    const int wm = (wid & 1) << 6;
    const int wn = (wid >> 1) << 5;
    f32x4 acc[4][2] = {};

    // staging coords (seg -> row, swizzled source column)
    const int ra0 = tid >> 2,           ca0 = ((tid & 3) ^ ((ra0 ^ (ra0 >> 2)) & 3)) << 3;
    const int ra1 = (256 + tid) >> 2,   ca1 = ((tid & 3) ^ ((ra1 ^ (ra1 >> 2)) & 3)) << 3;
    const int rb  = tid >> 2,           cb  = ca0;   // same formula, 64 rows
    const unsigned short* Ab = A + (size_t)m0 * KD;
    const unsigned short* Wb = W + (size_t)n0 * KD;
    // fragment-read swizzled slot (row&3 == lane&3, (row>>2)&3 == (lane&15)>>2)
    const int fx = (lane & 3) ^ ((lane & 15) >> 2);
    const int kslot = (((lane >> 4) ^ fx) << 3);
    const int frow = lane & 15;

    for (int k0 = 0; k0 < KD; k0 += 32) {
        __syncthreads();
        gload16(Ab + (size_t)ra0 * KD + k0 + ca0, &As[ra0][(tid & 3) << 3]);
        gload16(Ab + (size_t)ra1 * KD + k0 + ca1, &As[ra1][(tid & 3) << 3]);
        gload16(Wb + (size_t)rb  * KD + k0 + cb,  &Bs[rb][(tid & 3) << 3]);
        __syncthreads();
        bf16x8 af[4], bfr[2];
#pragma unroll
        for (int m = 0; m < 4; ++m)
            af[m] = *(const bf16x8*)&As[wm + (m << 4) + frow][kslot];
#pragma unroll
        for (int n = 0; n < 2; ++n)
            bfr[n] = *(const bf16x8*)&Bs[wn + (n << 4) + frow][kslot];
#pragma unroll
        for (int m = 0; m < 4; ++m)
#pragma unroll
            for (int n = 0; n < 2; ++n)
                acc[m][n] = __builtin_amdgcn_mfma_f32_16x16x32_bf16(af[m], bfr[n], acc[m][n], 0, 0, 0);
    }

    const int col0 = n0 + wn + (lane & 15);
    const int rbase = m0 + wm + ((lane >> 4) << 2);
#pragma unroll
    for (int n = 0; n < 2; ++n) {
        const int col = col0 + (n << 4);
        const float bz = sbias * bias[col];
#pragma unroll
        for (int m = 0; m < 4; ++m) {
#pragma unroll
            for (int r = 0; r < 4; ++r) {
                const size_t row = rbase + (m << 4) + r;
                float v = acc[m][n][r] + bz;
                if (EMODE == 0) {
                    ((float*)Cp)[row * 512 + col] = v;
                } else if (EMODE == 1) {
                    ((unsigned short*)Cp)[row * 512 + col] = f2bf(gelu_f(v));
                } else {
                    ((float*)Cp)[row * 512 + col] = v + xres[row * 512 + col];
                }
            }
        }
    }
}

// season: 512-pt real DFT bins 1..255 via Cooley-Tukey 16x32 (stage1 fp32,
// stage2 + |X|^2 in double), top-5 (tie -> lower index), cosine synthesis.
__global__ __launch_bounds__(256) void k_season(const float* __restrict__ x,
                                                float* __restrict__ out1) {
    __shared__ float xs[512];
    __shared__ float2 tab[512];
    __shared__ float2 tab32[32];
    __shared__ double2 tabd[512];
    __shared__ float2 Ys[512];
    __shared__ double wmag[4];
    __shared__ int widx[4];
    __shared__ float4 sel[5];

    const int tid = threadIdx.x;
    const long b = blockIdx.x;
    const float* xr = x + (b << 9);
    xs[tid] = xr[tid];
    xs[tid + 256] = xr[tid + 256];
    for (int i = tid; i < 512; i += 256) {
        double sv, cv;
        sincos((double)i * (3.14159265358979323846 / 256.0), &sv, &cv);
        tabd[i] = make_double2(cv, sv);
        tab[i] = make_float2((float)cv, (float)sv);
        if ((i & 15) == 0) tab32[i >> 4] = make_float2((float)cv, (float)sv);
    }
    __syncthreads();

    const int r = tid & 31;
    const int t0a = tid >> 5;
    float re0 = 0.f, im0 = 0.f, re1 = 0.f, im1 = 0.f;
    for (int t1 = 0; t1 < 32; ++t1) {
        float2 w = tab32[(r * t1) & 31];
        float xa = xs[(t1 << 4) + t0a];
        float xb = xs[(t1 << 4) + t0a + 8];
        re0 = fmaf(xa, w.x, re0); im0 = fmaf(xa, w.y, im0);
        re1 = fmaf(xb, w.x, re1); im1 = fmaf(xb, w.y, im1);
    }
    Ys[(t0a << 5) + r] = make_float2(re0, -im0);
    Ys[((t0a + 8) << 5) + r] = make_float2(re1, -im1);
    __syncthreads();

    double xre = 0.0, xim = 0.0, mag = -1.0;
    const int k = tid + 1;
    if (tid < 255) {
        const int rr = k & 31;
        for (int t0 = 0; t0 < 16; ++t0) {
            float2 y = Ys[(t0 << 5) + rr];
            double2 w = tabd[(k * t0) & 511];
            xre += (double)y.x * w.x + (double)y.y * w.y;
            xim += (double)y.y * w.x - (double)y.x * w.y;
        }
        mag = xre * xre + xim * xim;
    }

    double mymag = mag; int myk = k;
    for (int rnd = 0; rnd < 5; ++rnd) {
        double m = mymag; int i = myk;
#pragma unroll
        for (int off = 32; off > 0; off >>= 1) {
            double om = __shfl_xor(m, off);
            int oi = __shfl_xor(i, off);
            if (om > m || (om == m && oi < i)) { m = om; i = oi; }
        }
        if ((tid & 63) == 0) { wmag[tid >> 6] = m; widx[tid >> 6] = i; }
        __syncthreads();
        double gm = -2.0; int gi = 1 << 20;
#pragma unroll
        for (int w = 0; w < 4; ++w) {
            double pm = wmag[w]; int pi = widx[w];
            if (pm > gm || (pm == gm && pi < gi)) { gm = pm; gi = pi; }
        }
        if (tid < 255 && myk == gi) {
            sel[rnd] = make_float4((float)myk, (float)xre, (float)xim, 0.f);
            mymag = -1.0;
        }
        __syncthreads();
    }

#pragma unroll
    for (int half = 0; half < 2; ++half) {
        int t = tid + (half << 8);
        float acc = 0.f;
#pragma unroll
        for (int j = 0; j < 5; ++j) {
            float4 sj = sel[j];
            int kj = (int)sj.x;
            float2 w = tab[(kj * t) & 511];
            acc += sj.y * w.x - sj.z * w.y;
        }
        out1[(b << 9) + t] = 2.f * acc;
    }
}

__global__ __launch_bounds__(256) void k_zero(float4* __restrict__ p) {
    p[(long)blockIdx.x * 256 + threadIdx.x] = make_float4(0.f, 0.f, 0.f, 0.f);
}

extern "C" void kernel_launch(void* const* d_in, const int* in_sizes, int n_in,
                              void* d_out, int out_size, void* d_ws, size_t ws_size,
                              hipStream_t stream) {
    const float* x   = (const float*)d_in[0];
    const float* c1w = (const float*)d_in[1];
    const float* c1b = (const float*)d_in[2];
    const float* c3w = (const float*)d_in[3];
    const float* c3b = (const float*)d_in[4];
    const float* w1  = (const float*)d_in[5];
    const float* b1  = (const float*)d_in[6];
    const float* w2  = (const float*)d_in[7];
    const float* b2  = (const float*)d_in[8];
    const float* lg  = (const float*)d_in[9];
    const float* lb  = (const float*)d_in[10];

    float* out  = (float*)d_out;
    float* out1 = out + (long)BL_;          // season
    float* out2 = out + 2L * BL_;           // trend
    float* out3 = out + 3L * BL_;           // e

    // scratch carved from d_out (lifetimes ordered by the stream):
    unsigned short* h1   = (unsigned short*)d_out;          // 24 MB: [0, 24M)
    unsigned short* weff = h1 + (size_t)B_ * KT_;           // 1.5 MB at 24 MB
    unsigned short* w1b  = weff + (size_t)L_ * KT_;         // 0.5 MB
    unsigned short* w2b  = w1b + (size_t)L_ * L_;           // 0.5 MB (ends 26.5 MB < 32 MB)
    unsigned short* lnx  = (unsigned short*)d_out;          // 8 MB: [0, 8M)  (h1 dead)
    unsigned short* m1   = lnx + (size_t)BL_;               // 8 MB: [8M, 16M)

    // 1) conv1+GELU -> h1
    k_conv1<<<BL_ / 256, 256, 0, stream>>>(x, c1w, c1b, h1);
    // 2) weights -> bf16 (Weff collapse, w1, w2)
    k_prep<<<L_ * L_ / 256, 256, 0, stream>>>(c3w, w1, w2, weff, w1b, w2b);
    // 3) trend GEMM -> out2
    k_mgemm<0, KT_><<<dim3(64, 8), 256, 0, stream>>>(h1, weff, c3b, 0.875f, nullptr, out2);
    // 4) LN -> lnx (bf16)
    k_ln<<<B_ * 64 / 256, 256, 0, stream>>>(x, lg, lb, lnx);
    // 5) MLP1: GELU(lnx @ w1^T + b1) -> m1 (bf16)
    k_mgemm<1, 512><<<dim3(64, 8), 256, 0, stream>>>(lnx, w1b, b1, 1.0f, nullptr, m1);
    // 6) MLP2: m1 @ w2^T + b2 + x -> out3
    k_mgemm<2, 512><<<dim3(64, 8), 256, 0, stream>>>(m1, w2b, b2, 1.0f, x, out3);
    // 7) season -> out1 (weights region now dead)
    k_season<<<B_, 256, 0, stream>>>(x, out1);
    // 8) out0 = 0
    k_zero<<<4096, 256, 0, stream>>>((float4*)d_out);
}

// Round 5
// 153.875 us; speedup vs baseline: 2.7325x; 1.0247x over previous
//
#include <hip/hip_runtime.h>
#include <hip/hip_bf16.h>
#include <math.h>

#define B_ 8192
#define L_ 512
#define BL_ (B_ * L_)
#define KT_ 1536

using bf16x8 = __attribute__((ext_vector_type(8))) short;
using f32x4  = __attribute__((ext_vector_type(4))) float;

__device__ __forceinline__ float gelu_f(float v) {
    return 0.5f * v * (1.0f + erff(v * 0.70710678118654752f));
}
__device__ __forceinline__ float bf2f(unsigned short u) {
    return __uint_as_float(((unsigned int)u) << 16);
}
__device__ __forceinline__ unsigned short f2bf(float f) {
    unsigned int x = __float_as_uint(f);
    x += 0x7fffu + ((x >> 16) & 1u);   // RNE
    return (unsigned short)(x >> 16);
}
__device__ __forceinline__ void gload16(const void* g, void* l) {
    __builtin_amdgcn_global_load_lds(
        (const __attribute__((address_space(1))) unsigned int*)g,
        (__attribute__((address_space(3))) unsigned int*)l, 16, 0, 0);
}

// one-time twiddle tables -> d_ws: tabd(512 double2) | tab(512 float2) | tab32(32 float2)
__global__ __launch_bounds__(128) void k_tab(double2* __restrict__ tabd,
        float2* __restrict__ tab, float2* __restrict__ tab32) {
    int i = blockIdx.x * 128 + threadIdx.x;     // grid 4 -> 512
    double sv, cv;
    sincos((double)i * (3.14159265358979323846 / 256.0), &sv, &cv);
    tabd[i] = make_double2(cv, sv);
    tab[i] = make_float2((float)cv, (float)sv);
    if ((i & 15) == 0) tab32[i >> 4] = make_float2((float)cv, (float)sv);
}

// fused conv1(1->3ch,k=3,pad1)+GELU -> h1 bf16 [b][c][i]  AND  LayerNorm -> lnx bf16
// one block (256 thr) per row
__global__ __launch_bounds__(256) void k_pre(const float* __restrict__ x,
        const float* __restrict__ c1w, const float* __restrict__ c1b,
        const float* __restrict__ lg, const float* __restrict__ lbias,
        unsigned short* __restrict__ h1, unsigned short* __restrict__ lnx) {
    __shared__ float xs[512];
    __shared__ float red[8];
    const int tid = threadIdx.x;
    const long b = blockIdx.x;
    const float* xr = x + (b << 9);
    float x0 = xr[tid], x1 = xr[tid + 256];
    xs[tid] = x0; xs[tid + 256] = x1;
    float s = x0 + x1, ss = x0 * x0 + x1 * x1;
#pragma unroll
    for (int off = 32; off > 0; off >>= 1) {
        s += __shfl_xor(s, off);
        ss += __shfl_xor(ss, off);
    }
    if ((tid & 63) == 0) { red[tid >> 6] = s; red[4 + (tid >> 6)] = ss; }
    __syncthreads();
    s  = red[0] + red[1] + red[2] + red[3];
    ss = red[4] + red[5] + red[6] + red[7];
    const float mu = s * (1.f / 512.f);
    const float rs = rsqrtf(ss * (1.f / 512.f) - mu * mu + 1e-5f);
    float w[9], cb[3];
#pragma unroll
    for (int j = 0; j < 9; ++j) w[j] = c1w[j];
#pragma unroll
    for (int j = 0; j < 3; ++j) cb[j] = c1b[j];
#pragma unroll
    for (int half = 0; half < 2; ++half) {
        const int i = tid + (half << 8);
        const float xm = i ? xs[i - 1] : 0.f;
        const float xc = xs[i];
        const float xp = (i != 511) ? xs[i + 1] : 0.f;
        unsigned short* hb = h1 + b * KT_ + i;
#pragma unroll
        for (int c = 0; c < 3; ++c) {
            float v = w[c * 3] * xm + w[c * 3 + 1] * xc + w[c * 3 + 2] * xp + cb[c];
            hb[(long)c << 9] = f2bf(gelu_f(v));
        }
        lnx[(b << 9) + i] = f2bf(fmaf((xc - mu) * rs, lg[i], lbias[i]));
    }
}

// weight prep: Weff bf16 [512][1536] (collapsed conv3+poly), w1/w2 -> bf16 [N][K]
__global__ __launch_bounds__(256) void k_prep(const float* __restrict__ c3w,
        const float* __restrict__ w1, const float* __restrict__ w2,
        unsigned short* __restrict__ weff, unsigned short* __restrict__ w1b,
        unsigned short* __restrict__ w2b) {
    int idx = blockIdx.x * 256 + threadIdx.x;      // 512*512
    int o = idx >> 9, i = idx & 511;
    const float* t = c3w + (size_t)idx * 3;
    float t0 = t[0], t1 = t[1], t2 = t[2];
    size_t base = (size_t)o * KT_ + i;
    weff[base]        = f2bf(0.25f * t0 + 0.5f * t1);
    weff[base + 512]  = f2bf(0.125f * t0 + 0.25f * t1 + 0.5f * t2);
    weff[base + 1024] = f2bf(0.125f * t1 + 0.25f * t2);
    w1b[idx] = f2bf(w1[idx]);
    w2b[idx] = f2bf(w2[idx]);
}

// MFMA GEMM: C[M,N] = A[M,K](bf16) * W[N,K](bf16)^T + sbias*bias
// BM=128 BN=64 BK=32, 256 thr = 4 waves, wave tile 64x32 (4x2 frags 16x16x32)
// LDS XOR-swizzle both-sides (rule #21): dest linear, source pre-swizzled,
// read swizzled.  EMODE: 0 fp32; 1 GELU->bf16; 2 +xres fp32
template<int EMODE, int KD>
__global__ __launch_bounds__(256) void k_mgemm(
        const unsigned short* __restrict__ A, const unsigned short* __restrict__ W,
        const float* __restrict__ bias, float sbias,
        const float* __restrict__ xres, void* __restrict__ Cp) {
    __shared__ short As[128][32];
    __shared__ short Bs[64][32];
    const int tid = threadIdx.x;
    const int lane = tid & 63;
    const int wid = tid >> 6;
    const int m0 = blockIdx.x << 7;
    const int n0 = blockIdx.y << 6;
    const int wm = (wid & 1) << 6;
    const int wn = (wid >> 1) << 5;
    f32x4 acc[4][2] = {};

    const int ra0 = tid >> 2,           ca0 = ((tid & 3) ^ ((ra0 ^ (ra0 >> 2)) & 3)) << 3;
    const int ra1 = (256 + tid) >> 2,   ca1 = ((tid & 3) ^ ((ra1 ^ (ra1 >> 2)) & 3)) << 3;
    const int rb  = tid >> 2,           cb  = ca0;
    const unsigned short* Ab = A + (size_t)m0 * KD;
    const unsigned short* Wb = W + (size_t)n0 * KD;
    const int fx = (lane & 3) ^ ((lane & 15) >> 2);
    const int kslot = (((lane >> 4) ^ fx) << 3);
    const int frow = lane & 15;

    for (int k0 = 0; k0 < KD; k0 += 32) {
        __syncthreads();
        gload16(Ab + (size_t)ra0 * KD + k0 + ca0, &As[ra0][(tid & 3) << 3]);
        gload16(Ab + (size_t)ra1 * KD + k0 + ca1, &As[ra1][(tid & 3) << 3]);
        gload16(Wb + (size_t)rb  * KD + k0 + cb,  &Bs[rb][(tid & 3) << 3]);
        __syncthreads();
        bf16x8 af[4], bfr[2];
#pragma unroll
        for (int m = 0; m < 4; ++m)
            af[m] = *(const bf16x8*)&As[wm + (m << 4) + frow][kslot];
#pragma unroll
        for (int n = 0; n < 2; ++n)
            bfr[n] = *(const bf16x8*)&Bs[wn + (n << 4) + frow][kslot];
#pragma unroll
        for (int m = 0; m < 4; ++m)
#pragma unroll
            for (int n = 0; n < 2; ++n)
                acc[m][n] = __builtin_amdgcn_mfma_f32_16x16x32_bf16(af[m], bfr[n], acc[m][n], 0, 0, 0);
    }

    const int col0 = n0 + wn + (lane & 15);
    const int rbase = m0 + wm + ((lane >> 4) << 2);
#pragma unroll
    for (int n = 0; n < 2; ++n) {
        const int col = col0 + (n << 4);
        const float bz = sbias * bias[col];
#pragma unroll
        for (int m = 0; m < 4; ++m) {
#pragma unroll
            for (int r = 0; r < 4; ++r) {
                const size_t row = rbase + (m << 4) + r;
                float v = acc[m][n][r] + bz;
                if (EMODE == 0) {
                    ((float*)Cp)[row * 512 + col] = v;
                } else if (EMODE == 1) {
                    ((unsigned short*)Cp)[row * 512 + col] = f2bf(gelu_f(v));
                } else {
                    ((float*)Cp)[row * 512 + col] = v + xres[row * 512 + col];
                }
            }
        }
    }
}

// season: 512-pt real DFT bins 1..255 via CT 16x32 (stage1 fp32, stage2+|X|^2
// double), top-5 (tie -> lower index), cosine synthesis; also zeroes out0.
__global__ __launch_bounds__(256) void k_season(const float* __restrict__ x,
        const double2* __restrict__ gtabd, const float2* __restrict__ gtab,
        const float2* __restrict__ gtab32,
        float* __restrict__ out1, float* __restrict__ out0) {
    __shared__ float xs[512];
    __shared__ float2 tab[512];
    __shared__ float2 tab32[32];
    __shared__ double2 tabd[512];
    __shared__ float2 Ys[512];
    __shared__ double wmag[4];
    __shared__ int widx[4];
    __shared__ float4 sel[5];

    const int tid = threadIdx.x;
    const long b = blockIdx.x;
    const float* xr = x + (b << 9);
    xs[tid] = xr[tid];
    xs[tid + 256] = xr[tid + 256];
#pragma unroll
    for (int i = tid; i < 512; i += 256) {
        tabd[i] = gtabd[i];
        tab[i] = gtab[i];
    }
    if (tid < 32) tab32[tid] = gtab32[tid];
    __syncthreads();

    const int r = tid & 31;
    const int t0a = tid >> 5;
    float re0 = 0.f, im0 = 0.f, re1 = 0.f, im1 = 0.f;
    for (int t1 = 0; t1 < 32; ++t1) {
        float2 w = tab32[(r * t1) & 31];
        float xa = xs[(t1 << 4) + t0a];
        float xb = xs[(t1 << 4) + t0a + 8];
        re0 = fmaf(xa, w.x, re0); im0 = fmaf(xa, w.y, im0);
        re1 = fmaf(xb, w.x, re1); im1 = fmaf(xb, w.y, im1);
    }
    Ys[(t0a << 5) + r] = make_float2(re0, -im0);
    Ys[((t0a + 8) << 5) + r] = make_float2(re1, -im1);
    __syncthreads();

    double xre = 0.0, xim = 0.0, mag = -1.0;
    const int k = tid + 1;
    if (tid < 255) {
        const int rr = k & 31;
        for (int t0 = 0; t0 < 16; ++t0) {
            float2 y = Ys[(t0 << 5) + rr];
            double2 w = tabd[(k * t0) & 511];
            xre += (double)y.x * w.x + (double)y.y * w.y;
            xim += (double)y.y * w.x - (double)y.x * w.y;
        }
        mag = xre * xre + xim * xim;
    }

    double mymag = mag; int myk = k;
    for (int rnd = 0; rnd < 5; ++rnd) {
        double m = mymag; int i = myk;
#pragma unroll
        for (int off = 32; off > 0; off >>= 1) {
            double om = __shfl_xor(m, off);
            int oi = __shfl_xor(i, off);
            if (om > m || (om == m && oi < i)) { m = om; i = oi; }
        }
        if ((tid & 63) == 0) { wmag[tid >> 6] = m; widx[tid >> 6] = i; }
        __syncthreads();
        double gm = -2.0; int gi = 1 << 20;
#pragma unroll
        for (int w = 0; w < 4; ++w) {
            double pm = wmag[w]; int pi = widx[w];
            if (pm > gm || (pm == gm && pi < gi)) { gm = pm; gi = pi; }
        }
        if (tid < 255 && myk == gi) {
            sel[rnd] = make_float4((float)myk, (float)xre, (float)xim, 0.f);
            mymag = -1.0;
        }
        __syncthreads();
    }

#pragma unroll
    for (int half = 0; half < 2; ++half) {
        int t = tid + (half << 8);
        float acc = 0.f;
#pragma unroll
        for (int j = 0; j < 5; ++j) {
            float4 sj = sel[j];
            int kj = (int)sj.x;
            float2 w = tab[(kj * t) & 511];
            acc += sj.y * w.x - sj.z * w.y;
        }
        out1[(b << 9) + t] = 2.f * acc;
        out0[(b << 9) + t] = 0.f;
    }
}

extern "C" void kernel_launch(void* const* d_in, const int* in_sizes, int n_in,
                              void* d_out, int out_size, void* d_ws, size_t ws_size,
                              hipStream_t stream) {
    const float* x   = (const float*)d_in[0];
    const float* c1w = (const float*)d_in[1];
    const float* c1b = (const float*)d_in[2];
    const float* c3w = (const float*)d_in[3];
    const float* c3b = (const float*)d_in[4];
    const float* w1  = (const float*)d_in[5];
    const float* b1  = (const float*)d_in[6];
    const float* w2  = (const float*)d_in[7];
    const float* b2  = (const float*)d_in[8];
    const float* lg  = (const float*)d_in[9];
    const float* lb  = (const float*)d_in[10];

    float* out  = (float*)d_out;
    float* out1 = out + (long)BL_;          // season
    float* out2 = out + 2L * BL_;           // trend
    float* out3 = out + 3L * BL_;           // e

    // d_ws: twiddle tables (12.5 KB)
    double2* tabd = (double2*)d_ws;
    float2* tab   = (float2*)((char*)d_ws + 8192);
    float2* tab32 = (float2*)((char*)d_ws + 12288);

    // scratch in d_out (lifetimes ordered by the stream):
    unsigned short* h1   = (unsigned short*)d_out;          // 24 MB [0,24M): live till trend GEMM
    unsigned short* weff = h1 + (size_t)B_ * KT_;           // [24,25.5M)
    unsigned short* w1b  = weff + (size_t)L_ * KT_;         // [25.5,26M)
    unsigned short* w2b  = w1b + (size_t)L_ * L_;           // [26,26.5M): live till mgemm2
    unsigned short* lnx  = (unsigned short*)(out3);         // 8 MB in out3 region: live till mgemm1
    unsigned short* m1   = (unsigned short*)d_out;          // 8 MB [0,8M): after h1 dead

    // 1) twiddle tables (tiny)
    k_tab<<<4, 128, 0, stream>>>(tabd, tab, tab32);
    // 2) fused conv1+GELU -> h1 and LayerNorm -> lnx
    k_pre<<<B_, 256, 0, stream>>>(x, c1w, c1b, lg, lb, h1, lnx);
    // 3) weights -> bf16 (Weff collapse, w1, w2)
    k_prep<<<L_ * L_ / 256, 256, 0, stream>>>(c3w, w1, w2, weff, w1b, w2b);
    // 4) trend GEMM -> out2
    k_mgemm<0, KT_><<<dim3(64, 8), 256, 0, stream>>>(h1, weff, c3b, 0.875f, nullptr, out2);
    // 5) MLP1: GELU(lnx @ w1^T + b1) -> m1 (bf16; h1 now dead)
    k_mgemm<1, 512><<<dim3(64, 8), 256, 0, stream>>>(lnx, w1b, b1, 1.0f, nullptr, m1);
    // 6) MLP2: m1 @ w2^T + b2 + x -> out3 (lnx dead)
    k_mgemm<2, 512><<<dim3(64, 8), 256, 0, stream>>>(m1, w2b, b2, 1.0f, x, out3);
    // 7) season -> out1, zero -> out0 (all scratch dead)
    k_season<<<B_, 256, 0, stream>>>(x, tabd, tab, tab32, out1, out);
}

// Round 6
// 146.886 us; speedup vs baseline: 2.8625x; 1.0476x over previous
//
#include <hip/hip_runtime.h>
#include <hip/hip_bf16.h>
#include <math.h>

#define B_ 8192
#define L_ 512
#define BL_ (B_ * L_)
#define KT_ 1536

using bf16x8 = __attribute__((ext_vector_type(8))) short;
using f32x4  = __attribute__((ext_vector_type(4))) float;

__device__ __forceinline__ float gelu_f(float v) {
    return 0.5f * v * (1.0f + erff(v * 0.70710678118654752f));
}
__device__ __forceinline__ float bf2f(unsigned short u) {
    return __uint_as_float(((unsigned int)u) << 16);
}
__device__ __forceinline__ unsigned short f2bf(float f) {
    unsigned int x = __float_as_uint(f);
    x += 0x7fffu + ((x >> 16) & 1u);   // RNE
    return (unsigned short)(x >> 16);
}
__device__ __forceinline__ void gload16(const void* g, void* l) {
    __builtin_amdgcn_global_load_lds(
        (const __attribute__((address_space(1))) unsigned int*)g,
        (__attribute__((address_space(3))) unsigned int*)l, 16, 0, 0);
}

// one-time twiddle tables -> d_ws: tabd(512 double2) | tab(512 float2) | tab32(32 float2)
__global__ __launch_bounds__(128) void k_tab(double2* __restrict__ tabd,
        float2* __restrict__ tab, float2* __restrict__ tab32) {
    int i = blockIdx.x * 128 + threadIdx.x;     // grid 4 -> 512
    double sv, cv;
    sincos((double)i * (3.14159265358979323846 / 256.0), &sv, &cv);
    tabd[i] = make_double2(cv, sv);
    tab[i] = make_float2((float)cv, (float)sv);
    if ((i & 15) == 0) tab32[i >> 4] = make_float2((float)cv, (float)sv);
}

// fused conv1(1->3ch,k=3,pad1)+GELU -> h1 bf16 [b][c][i]  AND  LayerNorm -> lnx bf16
__global__ __launch_bounds__(256) void k_pre(const float* __restrict__ x,
        const float* __restrict__ c1w, const float* __restrict__ c1b,
        const float* __restrict__ lg, const float* __restrict__ lbias,
        unsigned short* __restrict__ h1, unsigned short* __restrict__ lnx) {
    __shared__ float xs[512];
    __shared__ float red[8];
    const int tid = threadIdx.x;
    const long b = blockIdx.x;
    const float* xr = x + (b << 9);
    float x0 = xr[tid], x1 = xr[tid + 256];
    xs[tid] = x0; xs[tid + 256] = x1;
    float s = x0 + x1, ss = x0 * x0 + x1 * x1;
#pragma unroll
    for (int off = 32; off > 0; off >>= 1) {
        s += __shfl_xor(s, off);
        ss += __shfl_xor(ss, off);
    }
    if ((tid & 63) == 0) { red[tid >> 6] = s; red[4 + (tid >> 6)] = ss; }
    __syncthreads();
    s  = red[0] + red[1] + red[2] + red[3];
    ss = red[4] + red[5] + red[6] + red[7];
    const float mu = s * (1.f / 512.f);
    const float rs = rsqrtf(ss * (1.f / 512.f) - mu * mu + 1e-5f);
    float w[9], cb[3];
#pragma unroll
    for (int j = 0; j < 9; ++j) w[j] = c1w[j];
#pragma unroll
    for (int j = 0; j < 3; ++j) cb[j] = c1b[j];
#pragma unroll
    for (int half = 0; half < 2; ++half) {
        const int i = tid + (half << 8);
        const float xm = i ? xs[i - 1] : 0.f;
        const float xc = xs[i];
        const float xp = (i != 511) ? xs[i + 1] : 0.f;
        unsigned short* hb = h1 + b * KT_ + i;
#pragma unroll
        for (int c = 0; c < 3; ++c) {
            float v = w[c * 3] * xm + w[c * 3 + 1] * xc + w[c * 3 + 2] * xp + cb[c];
            hb[(long)c << 9] = f2bf(gelu_f(v));
        }
        lnx[(b << 9) + i] = f2bf(fmaf((xc - mu) * rs, lg[i], lbias[i]));
    }
}

// weight prep: Weff bf16 [512][1536] (collapsed conv3+poly), w1/w2 -> bf16 [N][K]
__global__ __launch_bounds__(256) void k_prep(const float* __restrict__ c3w,
        const float* __restrict__ w1, const float* __restrict__ w2,
        unsigned short* __restrict__ weff, unsigned short* __restrict__ w1b,
        unsigned short* __restrict__ w2b) {
    int idx = blockIdx.x * 256 + threadIdx.x;      // 512*512
    int o = idx >> 9, i = idx & 511;
    const float* t = c3w + (size_t)idx * 3;
    float t0 = t[0], t1 = t[1], t2 = t[2];
    size_t base = (size_t)o * KT_ + i;
    weff[base]        = f2bf(0.25f * t0 + 0.5f * t1);
    weff[base + 512]  = f2bf(0.125f * t0 + 0.25f * t1 + 0.5f * t2);
    weff[base + 1024] = f2bf(0.125f * t1 + 0.25f * t2);
    w1b[idx] = f2bf(w1[idx]);
    w2b[idx] = f2bf(w2[idx]);
}

// MFMA GEMM: C[M,N] = A[M,K](bf16) * W[N,K](bf16)^T + sbias*bias
// BM=128 BN=64 BK=32, 4 waves, wave tile 64x32 (4x2 frags 16x16x32)
template<int EMODE, int KD>
__global__ __launch_bounds__(256) void k_mgemm(
        const unsigned short* __restrict__ A, const unsigned short* __restrict__ W,
        const float* __restrict__ bias, float sbias,
        const float* __restrict__ xres, void* __restrict__ Cp) {
    __shared__ short As[128][32];
    __shared__ short Bs[64][32];
    const int tid = threadIdx.x;
    const int lane = tid & 63;
    const int wid = tid >> 6;
    const int m0 = blockIdx.x << 7;
    const int n0 = blockIdx.y << 6;
    const int wm = (wid & 1) << 6;
    const int wn = (wid >> 1) << 5;
    f32x4 acc[4][2] = {};

    const int ra0 = tid >> 2,           ca0 = ((tid & 3) ^ ((ra0 ^ (ra0 >> 2)) & 3)) << 3;
    const int ra1 = (256 + tid) >> 2,   ca1 = ((tid & 3) ^ ((ra1 ^ (ra1 >> 2)) & 3)) << 3;
    const int rb  = tid >> 2,           cb  = ca0;
    const unsigned short* Ab = A + (size_t)m0 * KD;
    const unsigned short* Wb = W + (size_t)n0 * KD;
    const int fx = (lane & 3) ^ ((lane & 15) >> 2);
    const int kslot = (((lane >> 4) ^ fx) << 3);
    const int frow = lane & 15;

    for (int k0 = 0; k0 < KD; k0 += 32) {
        __syncthreads();
        gload16(Ab + (size_t)ra0 * KD + k0 + ca0, &As[ra0][(tid & 3) << 3]);
        gload16(Ab + (size_t)ra1 * KD + k0 + ca1, &As[ra1][(tid & 3) << 3]);
        gload16(Wb + (size_t)rb  * KD + k0 + cb,  &Bs[rb][(tid & 3) << 3]);
        __syncthreads();
        bf16x8 af[4], bfr[2];
#pragma unroll
        for (int m = 0; m < 4; ++m)
            af[m] = *(const bf16x8*)&As[wm + (m << 4) + frow][kslot];
#pragma unroll
        for (int n = 0; n < 2; ++n)
            bfr[n] = *(const bf16x8*)&Bs[wn + (n << 4) + frow][kslot];
#pragma unroll
        for (int m = 0; m < 4; ++m)
#pragma unroll
            for (int n = 0; n < 2; ++n)
                acc[m][n] = __builtin_amdgcn_mfma_f32_16x16x32_bf16(af[m], bfr[n], acc[m][n], 0, 0, 0);
    }

    const int col0 = n0 + wn + (lane & 15);
    const int rbase = m0 + wm + ((lane >> 4) << 2);
#pragma unroll
    for (int n = 0; n < 2; ++n) {
        const int col = col0 + (n << 4);
        const float bz = sbias * bias[col];
#pragma unroll
        for (int m = 0; m < 4; ++m) {
#pragma unroll
            for (int r = 0; r < 4; ++r) {
                const size_t row = rbase + (m << 4) + r;
                float v = acc[m][n][r] + bz;
                if (EMODE == 0) {
                    ((float*)Cp)[row * 512 + col] = v;
                } else if (EMODE == 1) {
                    ((unsigned short*)Cp)[row * 512 + col] = f2bf(gelu_f(v));
                } else {
                    ((float*)Cp)[row * 512 + col] = v + xres[row * 512 + col];
                }
            }
        }
    }
}

// season v2: wave-independent. Wave w owns bins with k&31 in [8w,8w+8).
// stage1 -> registers, stage2 gathers via __shfl, top-5 via packed-u64 wave
// butterfly (no barriers), 4x5 sorted-list merge after one barrier.
// Arithmetic order identical to v1 -> bit-identical output.
__global__ __launch_bounds__(256) void k_season(const float* __restrict__ x,
        const double2* __restrict__ gtabd, const float2* __restrict__ gtab,
        const float2* __restrict__ gtab32,
        float* __restrict__ out1, float* __restrict__ out0) {
    __shared__ float xs[512];
    __shared__ double2 tabd[512];
    __shared__ float2 tab[512];
    __shared__ float2 tab32[32];
    __shared__ unsigned long long wkey[4][5];
    __shared__ float2 wval[4][5];

    const int tid = threadIdx.x;
    const int w = tid >> 6, l = tid & 63;
    const long b = blockIdx.x;
    const float* xr = x + (b << 9);

    // staging (block-wide, one barrier)
    xs[tid] = xr[tid];
    xs[tid + 256] = xr[tid + 256];
    tabd[tid] = gtabd[tid];
    tabd[tid + 256] = gtabd[tid + 256];
    tab[tid] = gtab[tid];
    tab[tid + 256] = gtab[tid + 256];
    if (tid < 32) tab32[tid] = gtab32[tid];
    __syncthreads();                                   // barrier 1

    // stage 1 (registers): lane l computes Y[t0][rr], Y[t0+8][rr]
    const int rr = (w << 3) + (l & 7);
    const int t0 = l >> 3;                             // 0..7
    float re0 = 0.f, im0 = 0.f, re1 = 0.f, im1 = 0.f;
    for (int t1 = 0; t1 < 32; ++t1) {
        float2 wt = tab32[(rr * t1) & 31];
        float xa = xs[(t1 << 4) + t0];
        float xb = xs[(t1 << 4) + t0 + 8];
        re0 = fmaf(xa, wt.x, re0); im0 = fmaf(xa, wt.y, im0);
        re1 = fmaf(xb, wt.x, re1); im1 = fmaf(xb, wt.y, im1);
    }
    im0 = -im0; im1 = -im1;                            // Y = (re, -im)

    // stage 2 (double, shuffles): lane l handles k = 32*(l>>3) + rr
    const int k = ((l >> 3) << 5) + rr;                // 0..255, k=0 invalid
    double xre = 0.0, xim = 0.0;
#pragma unroll
    for (int t0i = 0; t0i < 16; ++t0i) {
        const int src = ((t0i & 7) << 3) + (l & 7);
        float yre = __shfl(t0i < 8 ? re0 : re1, src);
        float yim = __shfl(t0i < 8 ? im0 : im1, src);
        double2 wt = tabd[(k * t0i) & 511];
        xre += (double)yre * wt.x + (double)yim * wt.y;
        xim += (double)yim * wt.x - (double)yre * wt.y;
    }
    double mag = xre * xre + xim * xim;

    // packed key: mag's top-52 bits | (4095-k) -> tie breaks to lower k
    unsigned long long mykey = 0;
    if (k != 0) {
        unsigned long long mb = __double_as_longlong(mag);
        mykey = (mb & ~0xFFFull) | (unsigned long long)(4095 - k);
    }
    const float fre = (float)xre, fim = (float)xim;

    // wave-local top-5 (no barriers)
    for (int rnd = 0; rnd < 5; ++rnd) {
        unsigned long long rk = mykey;
#pragma unroll
        for (int off = 32; off > 0; off >>= 1) {
            unsigned long long ok = __shfl_xor(rk, off);
            rk = (ok > rk) ? ok : rk;
        }
        if (mykey == rk && rk != 0ull) {               // unique winner lane
            wkey[w][rnd] = rk;
            wval[w][rnd] = make_float2(fre, fim);
            mykey = 0;
        }
    }
    __syncthreads();                                   // barrier 2

    // merge 4 descending lists of 5 (every thread, redundantly, from LDS)
    float4 sel[5];
    int h0 = 0, h1 = 0, h2 = 0, h3 = 0;
#pragma unroll
    for (int rnd = 0; rnd < 5; ++rnd) {
        unsigned long long c0 = wkey[0][h0], c1 = wkey[1][h1];
        unsigned long long c2 = wkey[2][h2], c3 = wkey[3][h3];
        unsigned long long bk = c0; int bw = 0;
        if (c1 > bk) { bk = c1; bw = 1; }
        if (c2 > bk) { bk = c2; bw = 2; }
        if (c3 > bk) { bk = c3; bw = 3; }
        const int hs = (bw == 0) ? h0 : (bw == 1) ? h1 : (bw == 2) ? h2 : h3;
        float2 v = wval[bw][hs];
        h0 += (bw == 0); h1 += (bw == 1); h2 += (bw == 2); h3 += (bw == 3);
        const int kk = 4095 - (int)(bk & 0xFFFull);
        sel[rnd] = make_float4((float)kk, v.x, v.y, 0.f);
    }

    // synthesis + zero out0 (order identical to v1)
#pragma unroll
    for (int half = 0; half < 2; ++half) {
        int t = tid + (half << 8);
        float acc = 0.f;
#pragma unroll
        for (int j = 0; j < 5; ++j) {
            float4 sj = sel[j];
            int kj = (int)sj.x;
            float2 wt = tab[(kj * t) & 511];
            acc += sj.y * wt.x - sj.z * wt.y;
        }
        out1[(b << 9) + t] = 2.f * acc;
        out0[(b << 9) + t] = 0.f;
    }
}

extern "C" void kernel_launch(void* const* d_in, const int* in_sizes, int n_in,
                              void* d_out, int out_size, void* d_ws, size_t ws_size,
                              hipStream_t stream) {
    const float* x   = (const float*)d_in[0];
    const float* c1w = (const float*)d_in[1];
    const float* c1b = (const float*)d_in[2];
    const float* c3w = (const float*)d_in[3];
    const float* c3b = (const float*)d_in[4];
    const float* w1  = (const float*)d_in[5];
    const float* b1  = (const float*)d_in[6];
    const float* w2  = (const float*)d_in[7];
    const float* b2  = (const float*)d_in[8];
    const float* lg  = (const float*)d_in[9];
    const float* lb  = (const float*)d_in[10];

    float* out  = (float*)d_out;
    float* out1 = out + (long)BL_;          // season
    float* out2 = out + 2L * BL_;           // trend
    float* out3 = out + 3L * BL_;           // e

    // d_ws: twiddle tables (12.5 KB)
    double2* tabd = (double2*)d_ws;
    float2* tab   = (float2*)((char*)d_ws + 8192);
    float2* tab32 = (float2*)((char*)d_ws + 12288);

    // scratch in d_out (lifetimes ordered by the stream):
    unsigned short* h1   = (unsigned short*)d_out;          // 24 MB [0,24M): till trend GEMM
    unsigned short* weff = h1 + (size_t)B_ * KT_;           // [24,25.5M)
    unsigned short* w1b  = weff + (size_t)L_ * KT_;         // [25.5,26M)
    unsigned short* w2b  = w1b + (size_t)L_ * L_;           // [26,26.5M): till mgemm2
    unsigned short* lnx  = (unsigned short*)(out3);         // 8 MB in out3: till mgemm1
    unsigned short* m1   = (unsigned short*)d_out;          // 8 MB [0,8M): after h1 dead

    // 1) twiddle tables (tiny)
    k_tab<<<4, 128, 0, stream>>>(tabd, tab, tab32);
    // 2) fused conv1+GELU -> h1 and LayerNorm -> lnx
    k_pre<<<B_, 256, 0, stream>>>(x, c1w, c1b, lg, lb, h1, lnx);
    // 3) weights -> bf16 (Weff collapse, w1, w2)
    k_prep<<<L_ * L_ / 256, 256, 0, stream>>>(c3w, w1, w2, weff, w1b, w2b);
    // 4) trend GEMM -> out2
    k_mgemm<0, KT_><<<dim3(64, 8), 256, 0, stream>>>(h1, weff, c3b, 0.875f, nullptr, out2);
    // 5) MLP1: GELU(lnx @ w1^T + b1) -> m1 (bf16; h1 now dead)
    k_mgemm<1, 512><<<dim3(64, 8), 256, 0, stream>>>(lnx, w1b, b1, 1.0f, nullptr, m1);
    // 6) MLP2: m1 @ w2^T + b2 + x -> out3 (lnx dead)
    k_mgemm<2, 512><<<dim3(64, 8), 256, 0, stream>>>(m1, w2b, b2, 1.0f, x, out3);
    // 7) season -> out1, zero -> out0 (all scratch dead)
    k_season<<<B_, 256, 0, stream>>>(x, tabd, tab, tab32, out1, out);
}

// Round 9
// 142.061 us; speedup vs baseline: 2.9598x; 1.0340x over previous
//
#include <hip/hip_runtime.h>
#include <hip/hip_bf16.h>
#include <math.h>

#define B_ 8192
#define L_ 512
#define BL_ (B_ * L_)
#define KT_ 1536

using bf16x8 = __attribute__((ext_vector_type(8))) short;
using f32x4  = __attribute__((ext_vector_type(4))) float;

__device__ __forceinline__ float gelu_f(float v) {
    return 0.5f * v * (1.0f + erff(v * 0.70710678118654752f));
}
__device__ __forceinline__ float bf2f(unsigned short u) {
    return __uint_as_float(((unsigned int)u) << 16);
}
__device__ __forceinline__ unsigned short f2bf(float f) {
    unsigned int x = __float_as_uint(f);
    x += 0x7fffu + ((x >> 16) & 1u);   // RNE
    return (unsigned short)(x >> 16);
}
__device__ __forceinline__ void gload16(const void* g, void* l) {
    __builtin_amdgcn_global_load_lds(
        (const __attribute__((address_space(1))) unsigned int*)g,
        (__attribute__((address_space(3))) unsigned int*)l, 16, 0, 0);
}
// table-slot swizzle: spread bank groups for strided index sets
__device__ __forceinline__ int tswz(int e) { return e ^ ((e >> 3) & 7); }

// one-time twiddle tables -> d_ws: tabd(512 double2) | tab(512 float2) | tab32(32 float2)
__global__ __launch_bounds__(128) void k_tab(double2* __restrict__ tabd,
        float2* __restrict__ tab, float2* __restrict__ tab32) {
    int i = blockIdx.x * 128 + threadIdx.x;     // grid 4 -> 512
    double sv, cv;
    sincos((double)i * (3.14159265358979323846 / 256.0), &sv, &cv);
    tabd[i] = make_double2(cv, sv);
    tab[i] = make_float2((float)cv, (float)sv);
    if ((i & 15) == 0) tab32[i >> 4] = make_float2((float)cv, (float)sv);
}

// fused conv1(1->3ch,k=3,pad1)+GELU -> h1 bf16 [b][c][i]  AND  LayerNorm -> lnx bf16
__global__ __launch_bounds__(256) void k_pre(const float* __restrict__ x,
        const float* __restrict__ c1w, const float* __restrict__ c1b,
        const float* __restrict__ lg, const float* __restrict__ lbias,
        unsigned short* __restrict__ h1, unsigned short* __restrict__ lnx) {
    __shared__ float xs[512];
    __shared__ float red[8];
    const int tid = threadIdx.x;
    const long b = blockIdx.x;
    const float* xr = x + (b << 9);
    float x0 = xr[tid], x1 = xr[tid + 256];
    xs[tid] = x0; xs[tid + 256] = x1;
    float s = x0 + x1, ss = x0 * x0 + x1 * x1;
#pragma unroll
    for (int off = 32; off > 0; off >>= 1) {
        s += __shfl_xor(s, off);
        ss += __shfl_xor(ss, off);
    }
    if ((tid & 63) == 0) { red[tid >> 6] = s; red[4 + (tid >> 6)] = ss; }
    __syncthreads();
    s  = red[0] + red[1] + red[2] + red[3];
    ss = red[4] + red[5] + red[6] + red[7];
    const float mu = s * (1.f / 512.f);
    const float rs = rsqrtf(ss * (1.f / 512.f) - mu * mu + 1e-5f);
    float w[9], cb[3];
#pragma unroll
    for (int j = 0; j < 9; ++j) w[j] = c1w[j];
#pragma unroll
    for (int j = 0; j < 3; ++j) cb[j] = c1b[j];
#pragma unroll
    for (int half = 0; half < 2; ++half) {
        const int i = tid + (half << 8);
        const float xm = i ? xs[i - 1] : 0.f;
        const float xc = xs[i];
        const float xp = (i != 511) ? xs[i + 1] : 0.f;
        unsigned short* hb = h1 + b * KT_ + i;
#pragma unroll
        for (int c = 0; c < 3; ++c) {
            float v = w[c * 3] * xm + w[c * 3 + 1] * xc + w[c * 3 + 2] * xp + cb[c];
            hb[(long)c << 9] = f2bf(gelu_f(v));
        }
        lnx[(b << 9) + i] = f2bf(fmaf((xc - mu) * rs, lg[i], lbias[i]));
    }
}

// weight prep: Weff bf16 [512][1536] (collapsed conv3+poly), w1/w2 -> bf16 [N][K]
__global__ __launch_bounds__(256) void k_prep(const float* __restrict__ c3w,
        const float* __restrict__ w1, const float* __restrict__ w2,
        unsigned short* __restrict__ weff, unsigned short* __restrict__ w1b,
        unsigned short* __restrict__ w2b) {
    int idx = blockIdx.x * 256 + threadIdx.x;      // 512*512
    int o = idx >> 9, i = idx & 511;
    const float* t = c3w + (size_t)idx * 3;
    float t0 = t[0], t1 = t[1], t2 = t[2];
    size_t base = (size_t)o * KT_ + i;
    weff[base]        = f2bf(0.25f * t0 + 0.5f * t1);
    weff[base + 512]  = f2bf(0.125f * t0 + 0.25f * t1 + 0.5f * t2);
    weff[base + 1024] = f2bf(0.125f * t1 + 0.25f * t2);
    w1b[idx] = f2bf(w1[idx]);
    w2b[idx] = f2bf(w2[idx]);
}

// MFMA GEMM: C[M,N] = A[M,K](bf16) * W[N,K](bf16)^T + sbias*bias
// BM=128 BN=64 BK=32, 4 waves, wave tile 64x32 (4x2 frags 16x16x32)
template<int EMODE, int KD>
__global__ __launch_bounds__(256) void k_mgemm(
        const unsigned short* __restrict__ A, const unsigned short* __restrict__ W,
        const float* __restrict__ bias, float sbias,
        const float* __restrict__ xres, void* __restrict__ Cp) {
    __shared__ short As[128][32];
    __shared__ short Bs[64][32];
    const int tid = threadIdx.x;
    const int lane = tid & 63;
    const int wid = tid >> 6;
    const int m0 = blockIdx.x << 7;
    const int n0 = blockIdx.y << 6;
    const int wm = (wid & 1) << 6;
    const int wn = (wid >> 1) << 5;
    f32x4 acc[4][2] = {};

    const int ra0 = tid >> 2,           ca0 = ((tid & 3) ^ ((ra0 ^ (ra0 >> 2)) & 3)) << 3;
    const int ra1 = (256 + tid) >> 2,   ca1 = ((tid & 3) ^ ((ra1 ^ (ra1 >> 2)) & 3)) << 3;
    const int rb  = tid >> 2,           cb  = ca0;
    const unsigned short* Ab = A + (size_t)m0 * KD;
    const unsigned short* Wb = W + (size_t)n0 * KD;
    const int fx = (lane & 3) ^ ((lane & 15) >> 2);
    const int kslot = (((lane >> 4) ^ fx) << 3);
    const int frow = lane & 15;

    for (int k0 = 0; k0 < KD; k0 += 32) {
        __syncthreads();
        gload16(Ab + (size_t)ra0 * KD + k0 + ca0, &As[ra0][(tid & 3) << 3]);
        gload16(Ab + (size_t)ra1 * KD + k0 + ca1, &As[ra1][(tid & 3) << 3]);
        gload16(Wb + (size_t)rb  * KD + k0 + cb,  &Bs[rb][(tid & 3) << 3]);
        __syncthreads();
        bf16x8 af[4], bfr[2];
#pragma unroll
        for (int m = 0; m < 4; ++m)
            af[m] = *(const bf16x8*)&As[wm + (m << 4) + frow][kslot];
#pragma unroll
        for (int n = 0; n < 2; ++n)
            bfr[n] = *(const bf16x8*)&Bs[wn + (n << 4) + frow][kslot];
#pragma unroll
        for (int m = 0; m < 4; ++m)
#pragma unroll
            for (int n = 0; n < 2; ++n)
                acc[m][n] = __builtin_amdgcn_mfma_f32_16x16x32_bf16(af[m], bfr[n], acc[m][n], 0, 0, 0);
    }

    const int col0 = n0 + wn + (lane & 15);
    const int rbase = m0 + wm + ((lane >> 4) << 2);
#pragma unroll
    for (int n = 0; n < 2; ++n) {
        const int col = col0 + (n << 4);
        const float bz = sbias * bias[col];
#pragma unroll
        for (int m = 0; m < 4; ++m) {
#pragma unroll
            for (int r = 0; r < 4; ++r) {
                const size_t row = rbase + (m << 4) + r;
                float v = acc[m][n][r] + bz;
                if (EMODE == 0) {
                    ((float*)Cp)[row * 512 + col] = v;
                } else if (EMODE == 1) {
                    ((unsigned short*)Cp)[row * 512 + col] = f2bf(gelu_f(v));
                } else {
                    ((float*)Cp)[row * 512 + col] = v + xres[row * 512 + col];
                }
            }
        }
    }
}

// season v3: swizzled twiddle tables (bank spread), stage2 gather via LDS Ys
// (same-wave broadcast reads, no bpermute), arithmetic order identical to v1.
__global__ __launch_bounds__(256) void k_season(const float* __restrict__ x,
        const double2* __restrict__ gtabd, const float2* __restrict__ gtab,
        const float2* __restrict__ gtab32,
        float* __restrict__ out1, float* __restrict__ out0) {
    __shared__ float xs[512];
    __shared__ double2 tabd[512];   // slot tswz(e)
    __shared__ float2 tab[512];     // slot tswz(e)
    __shared__ float2 tab32[32];
    __shared__ float2 Ys[512];      // [t0][rr] (16x32)
    __shared__ unsigned long long wkey[4][5];
    __shared__ float2 wval[4][5];

    const int tid = threadIdx.x;
    const int w = tid >> 6, l = tid & 63;
    const long b = blockIdx.x;
    const float* xr = x + (b << 9);

    // staging (one barrier)
    xs[tid] = xr[tid];
    xs[tid + 256] = xr[tid + 256];
#pragma unroll
    for (int h = 0; h < 2; ++h) {
        const int i = tid + (h << 8);
        tabd[tswz(i)] = gtabd[i];
        tab[tswz(i)] = gtab[i];
    }
    if (tid < 32) tab32[tid] = gtab32[tid];
    __syncthreads();                                   // barrier 1

    // stage 1 (registers): lane l computes Y[t0][rr], Y[t0+8][rr]
    const int rr = (w << 3) + (l & 7);
    const int t0 = l >> 3;                             // 0..7
    float re0 = 0.f, im0 = 0.f, re1 = 0.f, im1 = 0.f;
#pragma unroll
    for (int t1 = 0; t1 < 32; ++t1) {
        float2 wt = tab32[(rr * t1) & 31];
        float xa = xs[(t1 << 4) + t0];
        float xb = xs[(t1 << 4) + t0 + 8];
        re0 = fmaf(xa, wt.x, re0); im0 = fmaf(xa, wt.y, im0);
        re1 = fmaf(xb, wt.x, re1); im1 = fmaf(xb, wt.y, im1);
    }
    // write Y to LDS (same-wave consumers only -> no barrier needed)
    Ys[(t0 << 5) + rr] = make_float2(re0, -im0);
    Ys[((t0 + 8) << 5) + rr] = make_float2(re1, -im1);

    // stage 2 (double): lane l handles k = 32*(l>>3) + rr
    const int k = ((l >> 3) << 5) + rr;                // 0..255, k=0 invalid
    double xre = 0.0, xim = 0.0;
#pragma unroll
    for (int t0i = 0; t0i < 16; ++t0i) {
        float2 y = Ys[(t0i << 5) + rr];                // 8-addr broadcast read
        const int e = (k * t0i) & 511;
        double2 wt = tabd[tswz(e)];
        xre += (double)y.x * wt.x + (double)y.y * wt.y;
        xim += (double)y.y * wt.x - (double)y.x * wt.y;
    }
    double mag = xre * xre + xim * xim;

    // packed key: mag's top-52 bits | (4095-k) -> tie breaks to lower k
    unsigned long long mykey = 0;
    if (k != 0) {
        unsigned long long mb = __double_as_longlong(mag);
        mykey = (mb & ~0xFFFull) | (unsigned long long)(4095 - k);
    }
    const float fre = (float)xre, fim = (float)xim;

    // wave-local top-5 (no barriers)
    for (int rnd = 0; rnd < 5; ++rnd) {
        unsigned long long rk = mykey;
#pragma unroll
        for (int off = 32; off > 0; off >>= 1) {
            unsigned long long ok = __shfl_xor(rk, off);
            rk = (ok > rk) ? ok : rk;
        }
        if (mykey == rk && rk != 0ull) {               // unique winner lane
            wkey[w][rnd] = rk;
            wval[w][rnd] = make_float2(fre, fim);
            mykey = 0;
        }
    }
    __syncthreads();                                   // barrier 2

    // merge 4 descending lists of 5 (every thread, redundantly, from LDS)
    float4 sel[5];
    int h0 = 0, h1 = 0, h2 = 0, h3 = 0;
#pragma unroll
    for (int rnd = 0; rnd < 5; ++rnd) {
        unsigned long long c0 = wkey[0][h0], c1 = wkey[1][h1];
        unsigned long long c2 = wkey[2][h2], c3 = wkey[3][h3];
        unsigned long long bk = c0; int bw = 0;
        if (c1 > bk) { bk = c1; bw = 1; }
        if (c2 > bk) { bk = c2; bw = 2; }
        if (c3 > bk) { bk = c3; bw = 3; }
        const int hs = (bw == 0) ? h0 : (bw == 1) ? h1 : (bw == 2) ? h2 : h3;
        float2 v = wval[bw][hs];
        h0 += (bw == 0); h1 += (bw == 1); h2 += (bw == 2); h3 += (bw == 3);
        const int kk = 4095 - (int)(bk & 0xFFFull);
        sel[rnd] = make_float4((float)kk, v.x, v.y, 0.f);
    }

    // synthesis + zero out0 (order identical to v1)
#pragma unroll
    for (int half = 0; half < 2; ++half) {
        int t = tid + (half << 8);
        float acc = 0.f;
#pragma unroll
        for (int j = 0; j < 5; ++j) {
            float4 sj = sel[j];
            int kj = (int)sj.x;
            const int e = (kj * t) & 511;
            float2 wt = tab[tswz(e)];
            acc += sj.y * wt.x - sj.z * wt.y;
        }
        out1[(b << 9) + t] = 2.f * acc;
        out0[(b << 9) + t] = 0.f;
    }
}

extern "C" void kernel_launch(void* const* d_in, const int* in_sizes, int n_in,
                              void* d_out, int out_size, void* d_ws, size_t ws_size,
                              hipStream_t stream) {
    const float* x   = (const float*)d_in[0];
    const float* c1w = (const float*)d_in[1];
    const float* c1b = (const float*)d_in[2];
    const float* c3w = (const float*)d_in[3];
    const float* c3b = (const float*)d_in[4];
    const float* w1  = (const float*)d_in[5];
    const float* b1  = (const float*)d_in[6];
    const float* w2  = (const float*)d_in[7];
    const float* b2  = (const float*)d_in[8];
    const float* lg  = (const float*)d_in[9];
    const float* lb  = (const float*)d_in[10];

    float* out  = (float*)d_out;
    float* out1 = out + (long)BL_;          // season
    float* out2 = out + 2L * BL_;           // trend
    float* out3 = out + 3L * BL_;           // e

    // d_ws: twiddle tables (12.5 KB)
    double2* tabd = (double2*)d_ws;
    float2* tab   = (float2*)((char*)d_ws + 8192);
    float2* tab32 = (float2*)((char*)d_ws + 12288);

    // scratch in d_out (lifetimes ordered by the stream):
    unsigned short* h1   = (unsigned short*)d_out;          // 24 MB [0,24M): till trend GEMM
    unsigned short* weff = h1 + (size_t)B_ * KT_;           // [24,25.5M)
    unsigned short* w1b  = weff + (size_t)L_ * KT_;         // [25.5,26M)
    unsigned short* w2b  = w1b + (size_t)L_ * L_;           // [26,26.5M): till mgemm2
    unsigned short* lnx  = (unsigned short*)(out3);         // 8 MB in out3: till mgemm1
    unsigned short* m1   = (unsigned short*)d_out;          // 8 MB [0,8M): after h1 dead

    // 1) twiddle tables (tiny)
    k_tab<<<4, 128, 0, stream>>>(tabd, tab, tab32);
    // 2) fused conv1+GELU -> h1 and LayerNorm -> lnx
    k_pre<<<B_, 256, 0, stream>>>(x, c1w, c1b, lg, lb, h1, lnx);
    // 3) weights -> bf16 (Weff collapse, w1, w2)
    k_prep<<<L_ * L_ / 256, 256, 0, stream>>>(c3w, w1, w2, weff, w1b, w2b);
    // 4) trend GEMM -> out2
    k_mgemm<0, KT_><<<dim3(64, 8), 256, 0, stream>>>(h1, weff, c3b, 0.875f, nullptr, out2);
    // 5) MLP1: GELU(lnx @ w1^T + b1) -> m1 (bf16; h1 now dead)
    k_mgemm<1, 512><<<dim3(64, 8), 256, 0, stream>>>(lnx, w1b, b1, 1.0f, nullptr, m1);
    // 6) MLP2: m1 @ w2^T + b2 + x -> out3 (lnx dead)
    k_mgemm<2, 512><<<dim3(64, 8), 256, 0, stream>>>(m1, w2b, b2, 1.0f, x, out3);
    // 7) season -> out1, zero -> out0 (all scratch dead)
    k_season<<<B_, 256, 0, stream>>>(x, tabd, tab, tab32, out1, out);
}

// Round 10
// 141.617 us; speedup vs baseline: 2.9690x; 1.0031x over previous
//
#include <hip/hip_runtime.h>
#include <hip/hip_bf16.h>
#include <math.h>

#define B_ 8192
#define L_ 512
#define BL_ (B_ * L_)
#define KT_ 1536

using bf16x8 = __attribute__((ext_vector_type(8))) short;
using f32x4  = __attribute__((ext_vector_type(4))) float;

__device__ __forceinline__ float gelu_f(float v) {
    return 0.5f * v * (1.0f + erff(v * 0.70710678118654752f));
}
__device__ __forceinline__ float bf2f(unsigned short u) {
    return __uint_as_float(((unsigned int)u) << 16);
}
__device__ __forceinline__ unsigned short f2bf(float f) {
    unsigned int x = __float_as_uint(f);
    x += 0x7fffu + ((x >> 16) & 1u);   // RNE
    return (unsigned short)(x >> 16);
}
__device__ __forceinline__ void gload16(const void* g, void* l) {
    __builtin_amdgcn_global_load_lds(
        (const __attribute__((address_space(1))) unsigned int*)g,
        (__attribute__((address_space(3))) unsigned int*)l, 16, 0, 0);
}

// one-time twiddle tables -> d_ws: tabd(512 double2) | tab(512 float2) | tab32(32 float2)
__global__ __launch_bounds__(128) void k_tab(double2* __restrict__ tabd,
        float2* __restrict__ tab, float2* __restrict__ tab32) {
    int i = blockIdx.x * 128 + threadIdx.x;     // grid 4 -> 512
    double sv, cv;
    sincos((double)i * (3.14159265358979323846 / 256.0), &sv, &cv);
    tabd[i] = make_double2(cv, sv);
    tab[i] = make_float2((float)cv, (float)sv);
    if ((i & 15) == 0) tab32[i >> 4] = make_float2((float)cv, (float)sv);
}

// fused conv1(1->3ch,k=3,pad1)+GELU -> h1 bf16 [b][c][i]  AND  LayerNorm -> lnx bf16
__global__ __launch_bounds__(256) void k_pre(const float* __restrict__ x,
        const float* __restrict__ c1w, const float* __restrict__ c1b,
        const float* __restrict__ lg, const float* __restrict__ lbias,
        unsigned short* __restrict__ h1, unsigned short* __restrict__ lnx) {
    __shared__ float xs[512];
    __shared__ float red[8];
    const int tid = threadIdx.x;
    const long b = blockIdx.x;
    const float* xr = x + (b << 9);
    float x0 = xr[tid], x1 = xr[tid + 256];
    xs[tid] = x0; xs[tid + 256] = x1;
    float s = x0 + x1, ss = x0 * x0 + x1 * x1;
#pragma unroll
    for (int off = 32; off > 0; off >>= 1) {
        s += __shfl_xor(s, off);
        ss += __shfl_xor(ss, off);
    }
    if ((tid & 63) == 0) { red[tid >> 6] = s; red[4 + (tid >> 6)] = ss; }
    __syncthreads();
    s  = red[0] + red[1] + red[2] + red[3];
    ss = red[4] + red[5] + red[6] + red[7];
    const float mu = s * (1.f / 512.f);
    const float rs = rsqrtf(ss * (1.f / 512.f) - mu * mu + 1e-5f);
    float w[9], cb[3];
#pragma unroll
    for (int j = 0; j < 9; ++j) w[j] = c1w[j];
#pragma unroll
    for (int j = 0; j < 3; ++j) cb[j] = c1b[j];
#pragma unroll
    for (int half = 0; half < 2; ++half) {
        const int i = tid + (half << 8);
        const float xm = i ? xs[i - 1] : 0.f;
        const float xc = xs[i];
        const float xp = (i != 511) ? xs[i + 1] : 0.f;
        unsigned short* hb = h1 + b * KT_ + i;
#pragma unroll
        for (int c = 0; c < 3; ++c) {
            float v = w[c * 3] * xm + w[c * 3 + 1] * xc + w[c * 3 + 2] * xp + cb[c];
            hb[(long)c << 9] = f2bf(gelu_f(v));
        }
        lnx[(b << 9) + i] = f2bf(fmaf((xc - mu) * rs, lg[i], lbias[i]));
    }
}

// weight prep: Weff bf16 [512][1536] (collapsed conv3+poly), w1/w2 -> bf16 [N][K]
__global__ __launch_bounds__(256) void k_prep(const float* __restrict__ c3w,
        const float* __restrict__ w1, const float* __restrict__ w2,
        unsigned short* __restrict__ weff, unsigned short* __restrict__ w1b,
        unsigned short* __restrict__ w2b) {
    int idx = blockIdx.x * 256 + threadIdx.x;      // 512*512
    int o = idx >> 9, i = idx & 511;
    const float* t = c3w + (size_t)idx * 3;
    float t0 = t[0], t1 = t[1], t2 = t[2];
    size_t base = (size_t)o * KT_ + i;
    weff[base]        = f2bf(0.25f * t0 + 0.5f * t1);
    weff[base + 512]  = f2bf(0.125f * t0 + 0.25f * t1 + 0.5f * t2);
    weff[base + 1024] = f2bf(0.125f * t1 + 0.25f * t2);
    w1b[idx] = f2bf(w1[idx]);
    w2b[idx] = f2bf(w2[idx]);
}

// MFMA GEMM: C[M,N] = A[M,K](bf16) * W[N,K](bf16)^T + sbias*bias
// BM=128 BN=64 BK=32, 4 waves, wave tile 64x32 (4x2 frags 16x16x32)
template<int EMODE, int KD>
__global__ __launch_bounds__(256) void k_mgemm(
        const unsigned short* __restrict__ A, const unsigned short* __restrict__ W,
        const float* __restrict__ bias, float sbias,
        const float* __restrict__ xres, void* __restrict__ Cp) {
    __shared__ short As[128][32];
    __shared__ short Bs[64][32];
    const int tid = threadIdx.x;
    const int lane = tid & 63;
    const int wid = tid >> 6;
    const int m0 = blockIdx.x << 7;
    const int n0 = blockIdx.y << 6;
    const int wm = (wid & 1) << 6;
    const int wn = (wid >> 1) << 5;
    f32x4 acc[4][2] = {};

    const int ra0 = tid >> 2,           ca0 = ((tid & 3) ^ ((ra0 ^ (ra0 >> 2)) & 3)) << 3;
    const int ra1 = (256 + tid) >> 2,   ca1 = ((tid & 3) ^ ((ra1 ^ (ra1 >> 2)) & 3)) << 3;
    const int rb  = tid >> 2,           cb  = ca0;
    const unsigned short* Ab = A + (size_t)m0 * KD;
    const unsigned short* Wb = W + (size_t)n0 * KD;
    const int fx = (lane & 3) ^ ((lane & 15) >> 2);
    const int kslot = (((lane >> 4) ^ fx) << 3);
    const int frow = lane & 15;

    for (int k0 = 0; k0 < KD; k0 += 32) {
        __syncthreads();
        gload16(Ab + (size_t)ra0 * KD + k0 + ca0, &As[ra0][(tid & 3) << 3]);
        gload16(Ab + (size_t)ra1 * KD + k0 + ca1, &As[ra1][(tid & 3) << 3]);
        gload16(Wb + (size_t)rb  * KD + k0 + cb,  &Bs[rb][(tid & 3) << 3]);
        __syncthreads();
        bf16x8 af[4], bfr[2];
#pragma unroll
        for (int m = 0; m < 4; ++m)
            af[m] = *(const bf16x8*)&As[wm + (m << 4) + frow][kslot];
#pragma unroll
        for (int n = 0; n < 2; ++n)
            bfr[n] = *(const bf16x8*)&Bs[wn + (n << 4) + frow][kslot];
#pragma unroll
        for (int m = 0; m < 4; ++m)
#pragma unroll
            for (int n = 0; n < 2; ++n)
                acc[m][n] = __builtin_amdgcn_mfma_f32_16x16x32_bf16(af[m], bfr[n], acc[m][n], 0, 0, 0);
    }

    const int col0 = n0 + wn + (lane & 15);
    const int rbase = m0 + wm + ((lane >> 4) << 2);
#pragma unroll
    for (int n = 0; n < 2; ++n) {
        const int col = col0 + (n << 4);
        const float bz = sbias * bias[col];
#pragma unroll
        for (int m = 0; m < 4; ++m) {
#pragma unroll
            for (int r = 0; r < 4; ++r) {
                const size_t row = rbase + (m << 4) + r;
                float v = acc[m][n][r] + bz;
                if (EMODE == 0) {
                    ((float*)Cp)[row * 512 + col] = v;
                } else if (EMODE == 1) {
                    ((unsigned short*)Cp)[row * 512 + col] = f2bf(gelu_f(v));
                } else {
                    ((float*)Cp)[row * 512 + col] = v + xres[row * 512 + col];
                }
            }
        }
    }
}

// season v4: twiddle tables read from GLOBAL (L1/L2-resident) -> DS-pipe
// offload; x packed as float2 pairs (one b64/iter in stage1); tab kept in
// LDS (linear) for synthesis gather. Arithmetic order identical to v1-v3.
__global__ __launch_bounds__(256) void k_season(const float* __restrict__ x,
        const double2* __restrict__ gtabd, const float2* __restrict__ gtab,
        const float2* __restrict__ gtab32,
        float* __restrict__ out1, float* __restrict__ out0) {
    __shared__ float2 xp[256];      // p = 8*t1 + t0 -> (x[16t1+t0], x[16t1+t0+8])
    __shared__ float2 tab[512];     // synthesis twiddles (linear)
    __shared__ float2 Ys[512];      // [t0][rr] (16x32)
    __shared__ unsigned long long wkey[4][5];
    __shared__ float2 wval[4][5];

    const int tid = threadIdx.x;
    const int w = tid >> 6, l = tid & 63;
    const long b = blockIdx.x;
    const float* xr = x + (b << 9);

    // staging: packed x pairs + synthesis table (one barrier)
    {
        const int t1s = tid >> 3, t0s = tid & 7;
        xp[tid] = make_float2(xr[(t1s << 4) + t0s], xr[(t1s << 4) + t0s + 8]);
        tab[tid] = gtab[tid];
        tab[tid + 256] = gtab[tid + 256];
    }
    __syncthreads();                                   // barrier 1

    // stage 1 (registers): lane l computes Y[t0][rr], Y[t0+8][rr]
    const int rr = (w << 3) + (l & 7);
    const int t0 = l >> 3;                             // 0..7
    float re0 = 0.f, im0 = 0.f, re1 = 0.f, im1 = 0.f;
#pragma unroll 8
    for (int t1 = 0; t1 < 32; ++t1) {
        float2 wt = gtab32[(rr * t1) & 31];            // global, L1-resident
        float2 xv = xp[(t1 << 3) + t0];                // b64 broadcast
        re0 = fmaf(xv.x, wt.x, re0); im0 = fmaf(xv.x, wt.y, im0);
        re1 = fmaf(xv.y, wt.x, re1); im1 = fmaf(xv.y, wt.y, im1);
    }
    // write Y to LDS (same-wave consumers only -> no barrier needed)
    Ys[(t0 << 5) + rr] = make_float2(re0, -im0);
    Ys[((t0 + 8) << 5) + rr] = make_float2(re1, -im1);

    // stage 2 (double): lane l handles k = 32*(l>>3) + rr
    const int k = ((l >> 3) << 5) + rr;                // 0..255, k=0 invalid
    double xre = 0.0, xim = 0.0;
#pragma unroll 4
    for (int t0i = 0; t0i < 16; ++t0i) {
        float2 y = Ys[(t0i << 5) + rr];                // 8-addr broadcast read
        double2 wt = gtabd[(k * t0i) & 511];           // global, L1-resident
        xre += (double)y.x * wt.x + (double)y.y * wt.y;
        xim += (double)y.y * wt.x - (double)y.x * wt.y;
    }
    double mag = xre * xre + xim * xim;

    // packed key: mag's top-52 bits | (4095-k) -> tie breaks to lower k
    unsigned long long mykey = 0;
    if (k != 0) {
        unsigned long long mb = __double_as_longlong(mag);
        mykey = (mb & ~0xFFFull) | (unsigned long long)(4095 - k);
    }
    const float fre = (float)xre, fim = (float)xim;

    // wave-local top-5 (no barriers)
    for (int rnd = 0; rnd < 5; ++rnd) {
        unsigned long long rk = mykey;
#pragma unroll
        for (int off = 32; off > 0; off >>= 1) {
            unsigned long long ok = __shfl_xor(rk, off);
            rk = (ok > rk) ? ok : rk;
        }
        if (mykey == rk && rk != 0ull) {               // unique winner lane
            wkey[w][rnd] = rk;
            wval[w][rnd] = make_float2(fre, fim);
            mykey = 0;
        }
    }
    __syncthreads();                                   // barrier 2

    // merge 4 descending lists of 5 (every thread, redundantly, from LDS)
    float4 sel[5];
    int h0 = 0, h1 = 0, h2 = 0, h3 = 0;
#pragma unroll
    for (int rnd = 0; rnd < 5; ++rnd) {
        unsigned long long c0 = wkey[0][h0], c1 = wkey[1][h1];
        unsigned long long c2 = wkey[2][h2], c3 = wkey[3][h3];
        unsigned long long bk = c0; int bw = 0;
        if (c1 > bk) { bk = c1; bw = 1; }
        if (c2 > bk) { bk = c2; bw = 2; }
        if (c3 > bk) { bk = c3; bw = 3; }
        const int hs = (bw == 0) ? h0 : (bw == 1) ? h1 : (bw == 2) ? h2 : h3;
        float2 v = wval[bw][hs];
        h0 += (bw == 0); h1 += (bw == 1); h2 += (bw == 2); h3 += (bw == 3);
        const int kk = 4095 - (int)(bk & 0xFFFull);
        sel[rnd] = make_float4((float)kk, v.x, v.y, 0.f);
    }

    // synthesis + zero out0 (order identical to v1)
#pragma unroll
    for (int half = 0; half < 2; ++half) {
        int t = tid + (half << 8);
        float acc = 0.f;
#pragma unroll
        for (int j = 0; j < 5; ++j) {
            float4 sj = sel[j];
            int kj = (int)sj.x;
            float2 wt = tab[(kj * t) & 511];
            acc += sj.y * wt.x - sj.z * wt.y;
        }
        out1[(b << 9) + t] = 2.f * acc;
        out0[(b << 9) + t] = 0.f;
    }
}

extern "C" void kernel_launch(void* const* d_in, const int* in_sizes, int n_in,
                              void* d_out, int out_size, void* d_ws, size_t ws_size,
                              hipStream_t stream) {
    const float* x   = (const float*)d_in[0];
    const float* c1w = (const float*)d_in[1];
    const float* c1b = (const float*)d_in[2];
    const float* c3w = (const float*)d_in[3];
    const float* c3b = (const float*)d_in[4];
    const float* w1  = (const float*)d_in[5];
    const float* b1  = (const float*)d_in[6];
    const float* w2  = (const float*)d_in[7];
    const float* b2  = (const float*)d_in[8];
    const float* lg  = (const float*)d_in[9];
    const float* lb  = (const float*)d_in[10];

    float* out  = (float*)d_out;
    float* out1 = out + (long)BL_;          // season
    float* out2 = out + 2L * BL_;           // trend
    float* out3 = out + 3L * BL_;           // e

    // d_ws: twiddle tables (12.5 KB)
    double2* tabd = (double2*)d_ws;
    float2* tab   = (float2*)((char*)d_ws + 8192);
    float2* tab32 = (float2*)((char*)d_ws + 12288);

    // scratch in d_out (lifetimes ordered by the stream):
    unsigned short* h1   = (unsigned short*)d_out;          // 24 MB [0,24M): till trend GEMM
    unsigned short* weff = h1 + (size_t)B_ * KT_;           // [24,25.5M)
    unsigned short* w1b  = weff + (size_t)L_ * KT_;         // [25.5,26M)
    unsigned short* w2b  = w1b + (size_t)L_ * L_;           // [26,26.5M): till mgemm2
    unsigned short* lnx  = (unsigned short*)(out3);         // 8 MB in out3: till mgemm1
    unsigned short* m1   = (unsigned short*)d_out;          // 8 MB [0,8M): after h1 dead

    // 1) twiddle tables (tiny)
    k_tab<<<4, 128, 0, stream>>>(tabd, tab, tab32);
    // 2) fused conv1+GELU -> h1 and LayerNorm -> lnx
    k_pre<<<B_, 256, 0, stream>>>(x, c1w, c1b, lg, lb, h1, lnx);
    // 3) weights -> bf16 (Weff collapse, w1, w2)
    k_prep<<<L_ * L_ / 256, 256, 0, stream>>>(c3w, w1, w2, weff, w1b, w2b);
    // 4) trend GEMM -> out2
    k_mgemm<0, KT_><<<dim3(64, 8), 256, 0, stream>>>(h1, weff, c3b, 0.875f, nullptr, out2);
    // 5) MLP1: GELU(lnx @ w1^T + b1) -> m1 (bf16; h1 now dead)
    k_mgemm<1, 512><<<dim3(64, 8), 256, 0, stream>>>(lnx, w1b, b1, 1.0f, nullptr, m1);
    // 6) MLP2: m1 @ w2^T + b2 + x -> out3 (lnx dead)
    k_mgemm<2, 512><<<dim3(64, 8), 256, 0, stream>>>(m1, w2b, b2, 1.0f, x, out3);
    // 7) season -> out1, zero -> out0 (all scratch dead)
    k_season<<<B_, 256, 0, stream>>>(x, tabd, tab, tab32, out1, out);
}

// Round 11
// 125.998 us; speedup vs baseline: 3.3371x; 1.1240x over previous
//
#include <hip/hip_runtime.h>
#include <hip/hip_bf16.h>
#include <math.h>

#define B_ 8192
#define L_ 512
#define BL_ (B_ * L_)
#define KT_ 1536

using bf16x8 = __attribute__((ext_vector_type(8))) short;
using f32x4  = __attribute__((ext_vector_type(4))) float;

__device__ __forceinline__ float gelu_f(float v) {
    return 0.5f * v * (1.0f + erff(v * 0.70710678118654752f));
}
__device__ __forceinline__ float bf2f(unsigned short u) {
    return __uint_as_float(((unsigned int)u) << 16);
}
__device__ __forceinline__ unsigned short f2bf(float f) {
    unsigned int x = __float_as_uint(f);
    x += 0x7fffu + ((x >> 16) & 1u);   // RNE
    return (unsigned short)(x >> 16);
}
__device__ __forceinline__ void gload16(const void* g, void* l) {
    __builtin_amdgcn_global_load_lds(
        (const __attribute__((address_space(1))) unsigned int*)g,
        (__attribute__((address_space(3))) unsigned int*)l, 16, 0, 0);
}

// fused conv1(1->3ch,k=3,pad1)+GELU -> h1 bf16 [b][c][i]  AND  LayerNorm -> lnx bf16
__global__ __launch_bounds__(256) void k_pre(const float* __restrict__ x,
        const float* __restrict__ c1w, const float* __restrict__ c1b,
        const float* __restrict__ lg, const float* __restrict__ lbias,
        unsigned short* __restrict__ h1, unsigned short* __restrict__ lnx) {
    __shared__ float xs[512];
    __shared__ float red[8];
    const int tid = threadIdx.x;
    const long b = blockIdx.x;
    const float* xr = x + (b << 9);
    float x0 = xr[tid], x1 = xr[tid + 256];
    xs[tid] = x0; xs[tid + 256] = x1;
    float s = x0 + x1, ss = x0 * x0 + x1 * x1;
#pragma unroll
    for (int off = 32; off > 0; off >>= 1) {
        s += __shfl_xor(s, off);
        ss += __shfl_xor(ss, off);
    }
    if ((tid & 63) == 0) { red[tid >> 6] = s; red[4 + (tid >> 6)] = ss; }
    __syncthreads();
    s  = red[0] + red[1] + red[2] + red[3];
    ss = red[4] + red[5] + red[6] + red[7];
    const float mu = s * (1.f / 512.f);
    const float rs = rsqrtf(ss * (1.f / 512.f) - mu * mu + 1e-5f);
    float w[9], cb[3];
#pragma unroll
    for (int j = 0; j < 9; ++j) w[j] = c1w[j];
#pragma unroll
    for (int j = 0; j < 3; ++j) cb[j] = c1b[j];
#pragma unroll
    for (int half = 0; half < 2; ++half) {
        const int i = tid + (half << 8);
        const float xm = i ? xs[i - 1] : 0.f;
        const float xc = xs[i];
        const float xp = (i != 511) ? xs[i + 1] : 0.f;
        unsigned short* hb = h1 + b * KT_ + i;
#pragma unroll
        for (int c = 0; c < 3; ++c) {
            float v = w[c * 3] * xm + w[c * 3 + 1] * xc + w[c * 3 + 2] * xp + cb[c];
            hb[(long)c << 9] = f2bf(gelu_f(v));
        }
        lnx[(b << 9) + i] = f2bf(fmaf((xc - mu) * rs, lg[i], lbias[i]));
    }
}

// weight prep: Weff bf16 [512][1536] (collapsed conv3+poly), w1/w2 -> bf16 [N][K]
// + twiddle tables (blocks 0-1): tabd(512 double2), tab(512 float2), tab32(32 float2)
__global__ __launch_bounds__(256) void k_prep(const float* __restrict__ c3w,
        const float* __restrict__ w1, const float* __restrict__ w2,
        unsigned short* __restrict__ weff, unsigned short* __restrict__ w1b,
        unsigned short* __restrict__ w2b,
        double2* __restrict__ tabd, float2* __restrict__ tab,
        float2* __restrict__ tab32) {
    int idx = blockIdx.x * 256 + threadIdx.x;      // 512*512
    if (idx < 512) {
        double sv, cv;
        sincos((double)idx * (3.14159265358979323846 / 256.0), &sv, &cv);
        tabd[idx] = make_double2(cv, sv);
        tab[idx] = make_float2((float)cv, (float)sv);
        if ((idx & 15) == 0) tab32[idx >> 4] = make_float2((float)cv, (float)sv);
    }
    int o = idx >> 9, i = idx & 511;
    const float* t = c3w + (size_t)idx * 3;
    float t0 = t[0], t1 = t[1], t2 = t[2];
    size_t base = (size_t)o * KT_ + i;
    weff[base]        = f2bf(0.25f * t0 + 0.5f * t1);
    weff[base + 512]  = f2bf(0.125f * t0 + 0.25f * t1 + 0.5f * t2);
    weff[base + 1024] = f2bf(0.125f * t1 + 0.25f * t2);
    w1b[idx] = f2bf(w1[idx]);
    w2b[idx] = f2bf(w2[idx]);
}

// MFMA GEMM: C[M,N] = A[M,K](bf16) * W[N,K](bf16)^T + sbias*bias
// BM=128 BN=64 BK=32, 4 waves, wave tile 64x32 (4x2 frags 16x16x32)
template<int EMODE, int KD>
__global__ __launch_bounds__(256) void k_mgemm(
        const unsigned short* __restrict__ A, const unsigned short* __restrict__ W,
        const float* __restrict__ bias, float sbias,
        const float* __restrict__ xres, void* __restrict__ Cp) {
    __shared__ short As[128][32];
    __shared__ short Bs[64][32];
    const int tid = threadIdx.x;
    const int lane = tid & 63;
    const int wid = tid >> 6;
    const int m0 = blockIdx.x << 7;
    const int n0 = blockIdx.y << 6;
    const int wm = (wid & 1) << 6;
    const int wn = (wid >> 1) << 5;
    f32x4 acc[4][2] = {};

    const int ra0 = tid >> 2,           ca0 = ((tid & 3) ^ ((ra0 ^ (ra0 >> 2)) & 3)) << 3;
    const int ra1 = (256 + tid) >> 2,   ca1 = ((tid & 3) ^ ((ra1 ^ (ra1 >> 2)) & 3)) << 3;
    const int rb  = tid >> 2,           cb  = ca0;
    const unsigned short* Ab = A + (size_t)m0 * KD;
    const unsigned short* Wb = W + (size_t)n0 * KD;
    const int fx = (lane & 3) ^ ((lane & 15) >> 2);
    const int kslot = (((lane >> 4) ^ fx) << 3);
    const int frow = lane & 15;

    for (int k0 = 0; k0 < KD; k0 += 32) {
        __syncthreads();
        gload16(Ab + (size_t)ra0 * KD + k0 + ca0, &As[ra0][(tid & 3) << 3]);
        gload16(Ab + (size_t)ra1 * KD + k0 + ca1, &As[ra1][(tid & 3) << 3]);
        gload16(Wb + (size_t)rb  * KD + k0 + cb,  &Bs[rb][(tid & 3) << 3]);
        __syncthreads();
        bf16x8 af[4], bfr[2];
#pragma unroll
        for (int m = 0; m < 4; ++m)
            af[m] = *(const bf16x8*)&As[wm + (m << 4) + frow][kslot];
#pragma unroll
        for (int n = 0; n < 2; ++n)
            bfr[n] = *(const bf16x8*)&Bs[wn + (n << 4) + frow][kslot];
#pragma unroll
        for (int m = 0; m < 4; ++m)
#pragma unroll
            for (int n = 0; n < 2; ++n)
                acc[m][n] = __builtin_amdgcn_mfma_f32_16x16x32_bf16(af[m], bfr[n], acc[m][n], 0, 0, 0);
    }

    const int col0 = n0 + wn + (lane & 15);
    const int rbase = m0 + wm + ((lane >> 4) << 2);
#pragma unroll
    for (int n = 0; n < 2; ++n) {
        const int col = col0 + (n << 4);
        const float bz = sbias * bias[col];
#pragma unroll
        for (int m = 0; m < 4; ++m) {
#pragma unroll
            for (int r = 0; r < 4; ++r) {
                const size_t row = rbase + (m << 4) + r;
                float v = acc[m][n][r] + bz;
                if (EMODE == 0) {
                    ((float*)Cp)[row * 512 + col] = v;
                } else if (EMODE == 1) {
                    ((unsigned short*)Cp)[row * 512 + col] = f2bf(gelu_f(v));
                } else {
                    ((float*)Cp)[row * 512 + col] = v + xres[row * 512 + col];
                }
            }
        }
    }
}

// season v5: 2 rows per block (amortized tables/addressing, 2x DP chains for
// ILP), strength-reduced twiddle indices. Per-bin arithmetic order identical
// to v1-v4 -> bit-identical output.
__global__ __launch_bounds__(256) void k_season(const float* __restrict__ x,
        const double2* __restrict__ gtabd, const float2* __restrict__ gtab,
        const float2* __restrict__ gtab32,
        float* __restrict__ out1, float* __restrict__ out0) {
    __shared__ float2 xp[2][256];   // p = 8*t1 + t0 -> (x[16t1+t0], x[16t1+t0+8])
    __shared__ float2 tab[512];     // synthesis twiddles (linear)
    __shared__ float2 Ys[2][512];   // [row][t0*32+rr]
    __shared__ unsigned long long wkey[2][4][5];
    __shared__ float2 wval[2][4][5];

    const int tid = threadIdx.x;
    const int w = tid >> 6, l = tid & 63;
    const long b = (long)blockIdx.x << 1;              // rows b, b+1
    const float* xr0 = x + (b << 9);
    const float* xr1 = xr0 + 512;

    // staging (one barrier)
    {
        const int t1s = tid >> 3, t0s = tid & 7;
        const int g = (t1s << 4) + t0s;
        xp[0][tid] = make_float2(xr0[g], xr0[g + 8]);
        xp[1][tid] = make_float2(xr1[g], xr1[g + 8]);
        tab[tid] = gtab[tid];
        tab[tid + 256] = gtab[tid + 256];
    }
    __syncthreads();                                   // barrier 1

    // stage 1: lane computes Y[t0][rr], Y[t0+8][rr] for both rows
    const int rr = (w << 3) + (l & 7);
    const int t0 = l >> 3;                             // 0..7
    float ra0 = 0.f, ia0 = 0.f, rb0 = 0.f, ib0 = 0.f;  // row0
    float ra1 = 0.f, ia1 = 0.f, rb1 = 0.f, ib1 = 0.f;  // row1
    int e32 = 0;
#pragma unroll
    for (int t1 = 0; t1 < 32; ++t1) {
        float2 wt = gtab32[e32];                       // (rr*t1)&31, L1-resident
        e32 = (e32 + rr) & 31;
        float2 v0 = xp[0][(t1 << 3) + t0];
        float2 v1 = xp[1][(t1 << 3) + t0];
        ra0 = fmaf(v0.x, wt.x, ra0); ia0 = fmaf(v0.x, wt.y, ia0);
        rb0 = fmaf(v0.y, wt.x, rb0); ib0 = fmaf(v0.y, wt.y, ib0);
        ra1 = fmaf(v1.x, wt.x, ra1); ia1 = fmaf(v1.x, wt.y, ia1);
        rb1 = fmaf(v1.y, wt.x, rb1); ib1 = fmaf(v1.y, wt.y, ib1);
    }
    // same-wave write->read (no barrier needed)
    Ys[0][(t0 << 5) + rr] = make_float2(ra0, -ia0);
    Ys[0][((t0 + 8) << 5) + rr] = make_float2(rb0, -ib0);
    Ys[1][(t0 << 5) + rr] = make_float2(ra1, -ia1);
    Ys[1][((t0 + 8) << 5) + rr] = make_float2(rb1, -ib1);

    // stage 2 (double): lane handles bin k for both rows
    const int k = ((l >> 3) << 5) + rr;                // 0..255, k=0 invalid
    double xre0 = 0.0, xim0 = 0.0, xre1 = 0.0, xim1 = 0.0;
    int e = 0;
#pragma unroll
    for (int t0i = 0; t0i < 16; ++t0i) {
        float2 y0 = Ys[0][(t0i << 5) + rr];
        float2 y1 = Ys[1][(t0i << 5) + rr];
        double2 wt = gtabd[e];                         // (k*t0i)&511
        e = (e + k) & 511;
        xre0 += (double)y0.x * wt.x + (double)y0.y * wt.y;
        xim0 += (double)y0.y * wt.x - (double)y0.x * wt.y;
        xre1 += (double)y1.x * wt.x + (double)y1.y * wt.y;
        xim1 += (double)y1.y * wt.x - (double)y1.x * wt.y;
    }

    // packed keys: mag top-52 bits | (4095-k) -> tie breaks to lower k
    unsigned long long key0 = 0, key1 = 0;
    if (k != 0) {
        double m0 = xre0 * xre0 + xim0 * xim0;
        double m1 = xre1 * xre1 + xim1 * xim1;
        key0 = (__double_as_longlong(m0) & ~0xFFFull) | (unsigned long long)(4095 - k);
        key1 = (__double_as_longlong(m1) & ~0xFFFull) | (unsigned long long)(4095 - k);
    }
    const float fre0 = (float)xre0, fim0 = (float)xim0;
    const float fre1 = (float)xre1, fim1 = (float)xim1;

    // wave-local top-5, both rows interleaved (no barriers)
    for (int rnd = 0; rnd < 5; ++rnd) {
        unsigned long long rk0 = key0, rk1 = key1;
#pragma unroll
        for (int off = 32; off > 0; off >>= 1) {
            unsigned long long o0 = __shfl_xor(rk0, off);
            unsigned long long o1 = __shfl_xor(rk1, off);
            rk0 = (o0 > rk0) ? o0 : rk0;
            rk1 = (o1 > rk1) ? o1 : rk1;
        }
        if (key0 == rk0 && rk0 != 0ull) {
            wkey[0][w][rnd] = rk0; wval[0][w][rnd] = make_float2(fre0, fim0); key0 = 0;
        }
        if (key1 == rk1 && rk1 != 0ull) {
            wkey[1][w][rnd] = rk1; wval[1][w][rnd] = make_float2(fre1, fim1); key1 = 0;
        }
    }
    __syncthreads();                                   // barrier 2

    // per row: merge 4 sorted lists of 5, then synthesis (+ zero out0)
#pragma unroll
    for (int row = 0; row < 2; ++row) {
        float4 sel[5];
        int h0 = 0, h1 = 0, h2 = 0, h3 = 0;
#pragma unroll
        for (int rnd = 0; rnd < 5; ++rnd) {
            unsigned long long c0 = wkey[row][0][h0], c1 = wkey[row][1][h1];
            unsigned long long c2 = wkey[row][2][h2], c3 = wkey[row][3][h3];
            unsigned long long bk = c0; int bw = 0;
            if (c1 > bk) { bk = c1; bw = 1; }
            if (c2 > bk) { bk = c2; bw = 2; }
            if (c3 > bk) { bk = c3; bw = 3; }
            const int hs = (bw == 0) ? h0 : (bw == 1) ? h1 : (bw == 2) ? h2 : h3;
            float2 v = wval[row][bw][hs];
            h0 += (bw == 0); h1 += (bw == 1); h2 += (bw == 2); h3 += (bw == 3);
            const int kk = 4095 - (int)(bk & 0xFFFull);
            sel[rnd] = make_float4((float)kk, v.x, v.y, 0.f);
        }
        const long ro = ((b + row) << 9);
#pragma unroll
        for (int half = 0; half < 2; ++half) {
            int t = tid + (half << 8);
            float acc = 0.f;
#pragma unroll
            for (int j = 0; j < 5; ++j) {
                float4 sj = sel[j];
                int kj = (int)sj.x;
                float2 wt = tab[(kj * t) & 511];
                acc += sj.y * wt.x - sj.z * wt.y;
            }
            out1[ro + t] = 2.f * acc;
            out0[ro + t] = 0.f;
        }
    }
}

extern "C" void kernel_launch(void* const* d_in, const int* in_sizes, int n_in,
                              void* d_out, int out_size, void* d_ws, size_t ws_size,
                              hipStream_t stream) {
    const float* x   = (const float*)d_in[0];
    const float* c1w = (const float*)d_in[1];
    const float* c1b = (const float*)d_in[2];
    const float* c3w = (const float*)d_in[3];
    const float* c3b = (const float*)d_in[4];
    const float* w1  = (const float*)d_in[5];
    const float* b1  = (const float*)d_in[6];
    const float* w2  = (const float*)d_in[7];
    const float* b2  = (const float*)d_in[8];
    const float* lg  = (const float*)d_in[9];
    const float* lb  = (const float*)d_in[10];

    float* out  = (float*)d_out;
    float* out1 = out + (long)BL_;          // season
    float* out2 = out + 2L * BL_;           // trend
    float* out3 = out + 3L * BL_;           // e

    // d_ws: twiddle tables (12.5 KB)
    double2* tabd = (double2*)d_ws;
    float2* tab   = (float2*)((char*)d_ws + 8192);
    float2* tab32 = (float2*)((char*)d_ws + 12288);

    // scratch in d_out (lifetimes ordered by the stream):
    unsigned short* h1   = (unsigned short*)d_out;          // 24 MB [0,24M): till trend GEMM
    unsigned short* weff = h1 + (size_t)B_ * KT_;           // [24,25.5M)
    unsigned short* w1b  = weff + (size_t)L_ * KT_;         // [25.5,26M)
    unsigned short* w2b  = w1b + (size_t)L_ * L_;           // [26,26.5M): till mgemm2
    unsigned short* lnx  = (unsigned short*)(out3);         // 8 MB in out3: till mgemm1
    unsigned short* m1   = (unsigned short*)d_out;          // 8 MB [0,8M): after h1 dead

    // 1) fused conv1+GELU -> h1 and LayerNorm -> lnx
    k_pre<<<B_, 256, 0, stream>>>(x, c1w, c1b, lg, lb, h1, lnx);
    // 2) weights -> bf16 + twiddle tables
    k_prep<<<L_ * L_ / 256, 256, 0, stream>>>(c3w, w1, w2, weff, w1b, w2b,
                                              tabd, tab, tab32);
    // 3) trend GEMM -> out2
    k_mgemm<0, KT_><<<dim3(64, 8), 256, 0, stream>>>(h1, weff, c3b, 0.875f, nullptr, out2);
    // 4) MLP1: GELU(lnx @ w1^T + b1) -> m1 (bf16; h1 now dead)
    k_mgemm<1, 512><<<dim3(64, 8), 256, 0, stream>>>(lnx, w1b, b1, 1.0f, nullptr, m1);
    // 5) MLP2: m1 @ w2^T + b2 + x -> out3 (lnx dead)
    k_mgemm<2, 512><<<dim3(64, 8), 256, 0, stream>>>(m1, w2b, b2, 1.0f, x, out3);
    // 6) season (2 rows/block) -> out1, zero -> out0 (all scratch dead)
    k_season<<<B_ / 2, 256, 0, stream>>>(x, tabd, tab, tab32, out1, out);
}

// Round 12
// 124.957 us; speedup vs baseline: 3.3649x; 1.0083x over previous
//
#include <hip/hip_runtime.h>
#include <hip/hip_bf16.h>
#include <math.h>

#define B_ 8192
#define L_ 512
#define BL_ (B_ * L_)
#define KT_ 1536

using bf16x8 = __attribute__((ext_vector_type(8))) short;
using f32x4  = __attribute__((ext_vector_type(4))) float;

__device__ __forceinline__ float gelu_f(float v) {
    return 0.5f * v * (1.0f + erff(v * 0.70710678118654752f));
}
__device__ __forceinline__ float bf2f(unsigned short u) {
    return __uint_as_float(((unsigned int)u) << 16);
}
__device__ __forceinline__ unsigned short f2bf(float f) {
    unsigned int x = __float_as_uint(f);
    x += 0x7fffu + ((x >> 16) & 1u);   // RNE
    return (unsigned short)(x >> 16);
}
__device__ __forceinline__ void gload16(const void* g, void* l) {
    __builtin_amdgcn_global_load_lds(
        (const __attribute__((address_space(1))) unsigned int*)g,
        (__attribute__((address_space(3))) unsigned int*)l, 16, 0, 0);
}

// fused conv1(1->3ch,k=3,pad1)+GELU -> h1 bf16 [b][c][i]  AND  LayerNorm -> lnx bf16
__global__ __launch_bounds__(256) void k_pre(const float* __restrict__ x,
        const float* __restrict__ c1w, const float* __restrict__ c1b,
        const float* __restrict__ lg, const float* __restrict__ lbias,
        unsigned short* __restrict__ h1, unsigned short* __restrict__ lnx) {
    __shared__ float xs[512];
    __shared__ float red[8];
    const int tid = threadIdx.x;
    const long b = blockIdx.x;
    const float* xr = x + (b << 9);
    float x0 = xr[tid], x1 = xr[tid + 256];
    xs[tid] = x0; xs[tid + 256] = x1;
    float s = x0 + x1, ss = x0 * x0 + x1 * x1;
#pragma unroll
    for (int off = 32; off > 0; off >>= 1) {
        s += __shfl_xor(s, off);
        ss += __shfl_xor(ss, off);
    }
    if ((tid & 63) == 0) { red[tid >> 6] = s; red[4 + (tid >> 6)] = ss; }
    __syncthreads();
    s  = red[0] + red[1] + red[2] + red[3];
    ss = red[4] + red[5] + red[6] + red[7];
    const float mu = s * (1.f / 512.f);
    const float rs = rsqrtf(ss * (1.f / 512.f) - mu * mu + 1e-5f);
    float w[9], cb[3];
#pragma unroll
    for (int j = 0; j < 9; ++j) w[j] = c1w[j];
#pragma unroll
    for (int j = 0; j < 3; ++j) cb[j] = c1b[j];
#pragma unroll
    for (int half = 0; half < 2; ++half) {
        const int i = tid + (half << 8);
        const float xm = i ? xs[i - 1] : 0.f;
        const float xc = xs[i];
        const float xp = (i != 511) ? xs[i + 1] : 0.f;
        unsigned short* hb = h1 + b * KT_ + i;
#pragma unroll
        for (int c = 0; c < 3; ++c) {
            float v = w[c * 3] * xm + w[c * 3 + 1] * xc + w[c * 3 + 2] * xp + cb[c];
            hb[(long)c << 9] = f2bf(gelu_f(v));
        }
        lnx[(b << 9) + i] = f2bf(fmaf((xc - mu) * rs, lg[i], lbias[i]));
    }
}

// weight prep: Weff bf16 [512][1536] (collapsed conv3+poly), w1/w2 -> bf16 [N][K]
// + twiddle tables (block 0-1): tabd(512 double2), tab(512 float2), tab32(32 float2)
__global__ __launch_bounds__(256) void k_prep(const float* __restrict__ c3w,
        const float* __restrict__ w1, const float* __restrict__ w2,
        unsigned short* __restrict__ weff, unsigned short* __restrict__ w1b,
        unsigned short* __restrict__ w2b,
        double2* __restrict__ tabd, float2* __restrict__ tab,
        float2* __restrict__ tab32) {
    int idx = blockIdx.x * 256 + threadIdx.x;      // 512*512
    if (idx < 512) {
        double sv, cv;
        sincos((double)idx * (3.14159265358979323846 / 256.0), &sv, &cv);
        tabd[idx] = make_double2(cv, sv);
        tab[idx] = make_float2((float)cv, (float)sv);
        if ((idx & 15) == 0) tab32[idx >> 4] = make_float2((float)cv, (float)sv);
    }
    int o = idx >> 9, i = idx & 511;
    const float* t = c3w + (size_t)idx * 3;
    float t0 = t[0], t1 = t[1], t2 = t[2];
    size_t base = (size_t)o * KT_ + i;
    weff[base]        = f2bf(0.25f * t0 + 0.5f * t1);
    weff[base + 512]  = f2bf(0.125f * t0 + 0.25f * t1 + 0.5f * t2);
    weff[base + 1024] = f2bf(0.125f * t1 + 0.25f * t2);
    w1b[idx] = f2bf(w1[idx]);
    w2b[idx] = f2bf(w2[idx]);
}

// MFMA GEMM: C[M,N] = A[M,K](bf16) * W[N,K](bf16)^T + sbias*bias
// BM=128 BN=64 BK=64, 4 waves, wave tile 64x32 (4x2 frags 16x16x32, 2 k-substeps)
// LDS [*][64] (128B rows): slot-XOR swizzle slot^=(row&7); source pre-swizzled,
// dest linear (= base + tid*16), read swizzled (rule #21).
template<int EMODE, int KD>
__global__ __launch_bounds__(256) void k_mgemm(
        const unsigned short* __restrict__ A, const unsigned short* __restrict__ W,
        const float* __restrict__ bias, float sbias,
        const float* __restrict__ xres, void* __restrict__ Cp) {
    __shared__ short As[128][64];
    __shared__ short Bs[64][64];
    const int tid = threadIdx.x;
    const int lane = tid & 63;
    const int wid = tid >> 6;
    const int m0 = blockIdx.x << 7;
    const int n0 = blockIdx.y << 6;
    const int wm = (wid & 1) << 6;
    const int wn = (wid >> 1) << 5;
    f32x4 acc[4][2] = {};

    const int srow = tid >> 3;          // 0..31 per segment
    const int schunk = tid & 7;         // 16B chunk within 64-col row
    const unsigned short* Ab = A + (size_t)m0 * KD;
    const unsigned short* Wb = W + (size_t)n0 * KD;
    const int frow = lane & 15;
    const int fsw = frow & 7;
    const int s0 = lane >> 4;           // k-subslot 0..3

    for (int k0 = 0; k0 < KD; k0 += 64) {
        __syncthreads();
#pragma unroll
        for (int seg = 0; seg < 4; ++seg) {
            const int r = (seg << 5) + srow;
            const int c = (schunk ^ (r & 7)) << 3;
            gload16(Ab + (size_t)r * KD + k0 + c, &As[r][schunk << 3]);
        }
#pragma unroll
        for (int seg = 0; seg < 2; ++seg) {
            const int r = (seg << 5) + srow;
            const int c = (schunk ^ (r & 7)) << 3;
            gload16(Wb + (size_t)r * KD + k0 + c, &Bs[r][schunk << 3]);
        }
        __syncthreads();
#pragma unroll
        for (int kk = 0; kk < 2; ++kk) {
            bf16x8 af[4], bfr[2];
            const int sl = (kk << 2) + s0;
#pragma unroll
            for (int m = 0; m < 4; ++m)
                af[m] = *(const bf16x8*)&As[wm + (m << 4) + frow][(sl ^ fsw) << 3];
#pragma unroll
            for (int n = 0; n < 2; ++n)
                bfr[n] = *(const bf16x8*)&Bs[wn + (n << 4) + frow][(sl ^ fsw) << 3];
#pragma unroll
            for (int m = 0; m < 4; ++m)
#pragma unroll
                for (int n = 0; n < 2; ++n)
                    acc[m][n] = __builtin_amdgcn_mfma_f32_16x16x32_bf16(af[m], bfr[n], acc[m][n], 0, 0, 0);
        }
    }

    const int col0 = n0 + wn + (lane & 15);
    const int rbase = m0 + wm + ((lane >> 4) << 2);
#pragma unroll
    for (int n = 0; n < 2; ++n) {
        const int col = col0 + (n << 4);
        const float bz = sbias * bias[col];
#pragma unroll
        for (int m = 0; m < 4; ++m) {
#pragma unroll
            for (int r = 0; r < 4; ++r) {
                const size_t row = rbase + (m << 4) + r;
                float v = acc[m][n][r] + bz;
                if (EMODE == 0) {
                    ((float*)Cp)[row * 512 + col] = v;
                } else if (EMODE == 1) {
                    ((unsigned short*)Cp)[row * 512 + col] = f2bf(gelu_f(v));
                } else {
                    ((float*)Cp)[row * 512 + col] = v + xres[row * 512 + col];
                }
            }
        }
    }
}

// season v6: 4 rows per block, float4-packed xp/Ys (2 rows per b128).
// Per-row/bin arithmetic order identical to v1-v5 -> bit-identical output.
__global__ __launch_bounds__(256) void k_season(const float* __restrict__ x,
        const double2* __restrict__ gtabd, const float2* __restrict__ gtab,
        const float2* __restrict__ gtab32,
        float* __restrict__ out1, float* __restrict__ out0) {
    __shared__ float4 xpA[256];     // (r0[g], r0[g+8], r1[g], r1[g+8]), g=16*t1+t0
    __shared__ float4 xpB[256];     // rows 2,3
    __shared__ float2 tab[512];     // synthesis twiddles (linear)
    __shared__ float4 YsA[512];     // (r0.re, r0.im, r1.re, r1.im) at [t0*32+rr]
    __shared__ float4 YsB[512];     // rows 2,3
    __shared__ unsigned long long wkey[4][4][5];   // [row][wave][rnd]
    __shared__ float2 wval[4][4][5];

    const int tid = threadIdx.x;
    const int w = tid >> 6, l = tid & 63;
    const long b = (long)blockIdx.x << 2;              // rows b..b+3
    const float* xr0 = x + (b << 9);
    const float* xr1 = xr0 + 512;
    const float* xr2 = xr0 + 1024;
    const float* xr3 = xr0 + 1536;

    // staging (one barrier)
    {
        const int g = ((tid >> 3) << 4) + (tid & 7);
        xpA[tid] = make_float4(xr0[g], xr0[g + 8], xr1[g], xr1[g + 8]);
        xpB[tid] = make_float4(xr2[g], xr2[g + 8], xr3[g], xr3[g + 8]);
        tab[tid] = gtab[tid];
        tab[tid + 256] = gtab[tid + 256];
    }
    __syncthreads();                                   // barrier 1

    // stage 1: lane computes Y[t0][rr], Y[t0+8][rr] for 4 rows
    const int rr = (w << 3) + (l & 7);
    const int t0 = l >> 3;                             // 0..7
    float ar[4] = {}, ai[4] = {}, br[4] = {}, bi[4] = {};
    int e32 = 0;
#pragma unroll
    for (int t1 = 0; t1 < 32; ++t1) {
        float2 wt = gtab32[e32];                       // (rr*t1)&31, L1-resident
        e32 = (e32 + rr) & 31;
        float4 vA = xpA[(t1 << 3) + t0];
        float4 vB = xpB[(t1 << 3) + t0];
        ar[0] = fmaf(vA.x, wt.x, ar[0]); ai[0] = fmaf(vA.x, wt.y, ai[0]);
        br[0] = fmaf(vA.y, wt.x, br[0]); bi[0] = fmaf(vA.y, wt.y, bi[0]);
        ar[1] = fmaf(vA.z, wt.x, ar[1]); ai[1] = fmaf(vA.z, wt.y, ai[1]);
        br[1] = fmaf(vA.w, wt.x, br[1]); bi[1] = fmaf(vA.w, wt.y, bi[1]);
        ar[2] = fmaf(vB.x, wt.x, ar[2]); ai[2] = fmaf(vB.x, wt.y, ai[2]);
        br[2] = fmaf(vB.y, wt.x, br[2]); bi[2] = fmaf(vB.y, wt.y, bi[2]);
        ar[3] = fmaf(vB.z, wt.x, ar[3]); ai[3] = fmaf(vB.z, wt.y, ai[3]);
        br[3] = fmaf(vB.w, wt.x, br[3]); bi[3] = fmaf(vB.w, wt.y, bi[3]);
    }
    // same-wave write->read (no barrier needed)
    YsA[(t0 << 5) + rr] = make_float4(ar[0], -ai[0], ar[1], -ai[1]);
    YsA[((t0 + 8) << 5) + rr] = make_float4(br[0], -bi[0], br[1], -bi[1]);
    YsB[(t0 << 5) + rr] = make_float4(ar[2], -ai[2], ar[3], -ai[3]);
    YsB[((t0 + 8) << 5) + rr] = make_float4(br[2], -bi[2], br[3], -bi[3]);

    // stage 2 (double): lane handles bin k for 4 rows
    const int k = ((l >> 3) << 5) + rr;                // 0..255, k=0 invalid
    double xre[4] = {}, xim[4] = {};
    int e = 0;
#pragma unroll
    for (int t0i = 0; t0i < 16; ++t0i) {
        float4 yA = YsA[(t0i << 5) + rr];
        float4 yB = YsB[(t0i << 5) + rr];
        double2 wt = gtabd[e];                         // (k*t0i)&511
        e = (e + k) & 511;
        xre[0] += (double)yA.x * wt.x + (double)yA.y * wt.y;
        xim[0] += (double)yA.y * wt.x - (double)yA.x * wt.y;
        xre[1] += (double)yA.z * wt.x + (double)yA.w * wt.y;
        xim[1] += (double)yA.w * wt.x - (double)yA.z * wt.y;
        xre[2] += (double)yB.x * wt.x + (double)yB.y * wt.y;
        xim[2] += (double)yB.y * wt.x - (double)yB.x * wt.y;
        xre[3] += (double)yB.z * wt.x + (double)yB.w * wt.y;
        xim[3] += (double)yB.w * wt.x - (double)yB.z * wt.y;
    }

    // packed keys: mag top-52 bits | (4095-k) -> tie breaks to lower k
    unsigned long long key[4] = {};
    float fre[4], fim[4];
#pragma unroll
    for (int r = 0; r < 4; ++r) {
        if (k != 0) {
            double m = xre[r] * xre[r] + xim[r] * xim[r];
            key[r] = (__double_as_longlong(m) & ~0xFFFull)
                   | (unsigned long long)(4095 - k);
        }
        fre[r] = (float)xre[r]; fim[r] = (float)xim[r];
    }

    // wave-local top-5, 4 rows interleaved (no barriers)
    for (int rnd = 0; rnd < 5; ++rnd) {
        unsigned long long rk[4] = {key[0], key[1], key[2], key[3]};
#pragma unroll
        for (int off = 32; off > 0; off >>= 1) {
#pragma unroll
            for (int r = 0; r < 4; ++r) {
                unsigned long long o = __shfl_xor(rk[r], off);
                rk[r] = (o > rk[r]) ? o : rk[r];
            }
        }
#pragma unroll
        for (int r = 0; r < 4; ++r) {
            if (key[r] == rk[r] && rk[r] != 0ull) {    // unique winner lane
                wkey[r][w][rnd] = rk[r];
                wval[r][w][rnd] = make_float2(fre[r], fim[r]);
                key[r] = 0;
            }
        }
    }
    __syncthreads();                                   // barrier 2

    // per row: merge 4 sorted lists of 5, then synthesis (+ zero out0)
#pragma unroll
    for (int row = 0; row < 4; ++row) {
        float4 sel[5];
        int h0 = 0, h1 = 0, h2 = 0, h3 = 0;
#pragma unroll
        for (int rnd = 0; rnd < 5; ++rnd) {
            unsigned long long c0 = wkey[row][0][h0], c1 = wkey[row][1][h1];
            unsigned long long c2 = wkey[row][2][h2], c3 = wkey[row][3][h3];
            unsigned long long bk = c0; int bw = 0;
            if (c1 > bk) { bk = c1; bw = 1; }
            if (c2 > bk) { bk = c2; bw = 2; }
            if (c3 > bk) { bk = c3; bw = 3; }
            const int hs = (bw == 0) ? h0 : (bw == 1) ? h1 : (bw == 2) ? h2 : h3;
            float2 v = wval[row][bw][hs];
            h0 += (bw == 0); h1 += (bw == 1); h2 += (bw == 2); h3 += (bw == 3);
            const int kk = 4095 - (int)(bk & 0xFFFull);
            sel[rnd] = make_float4((float)kk, v.x, v.y, 0.f);
        }
        const long ro = ((b + row) << 9);
#pragma unroll
        for (int half = 0; half < 2; ++half) {
            int t = tid + (half << 8);
            float acc = 0.f;
#pragma unroll
            for (int j = 0; j < 5; ++j) {
                float4 sj = sel[j];
                int kj = (int)sj.x;
                float2 wt = tab[(kj * t) & 511];
                acc += sj.y * wt.x - sj.z * wt.y;
            }
            out1[ro + t] = 2.f * acc;
            out0[ro + t] = 0.f;
        }
    }
}

extern "C" void kernel_launch(void* const* d_in, const int* in_sizes, int n_in,
                              void* d_out, int out_size, void* d_ws, size_t ws_size,
                              hipStream_t stream) {
    const float* x   = (const float*)d_in[0];
    const float* c1w = (const float*)d_in[1];
    const float* c1b = (const float*)d_in[2];
    const float* c3w = (const float*)d_in[3];
    const float* c3b = (const float*)d_in[4];
    const float* w1  = (const float*)d_in[5];
    const float* b1  = (const float*)d_in[6];
    const float* w2  = (const float*)d_in[7];
    const float* b2  = (const float*)d_in[8];
    const float* lg  = (const float*)d_in[9];
    const float* lb  = (const float*)d_in[10];

    float* out  = (float*)d_out;
    float* out1 = out + (long)BL_;          // season
    float* out2 = out + 2L * BL_;           // trend
    float* out3 = out + 3L * BL_;           // e

    // d_ws: twiddle tables (12.5 KB)
    double2* tabd = (double2*)d_ws;
    float2* tab   = (float2*)((char*)d_ws + 8192);
    float2* tab32 = (float2*)((char*)d_ws + 12288);

    // scratch in d_out (lifetimes ordered by the stream):
    unsigned short* h1   = (unsigned short*)d_out;          // 24 MB [0,24M): till trend GEMM
    unsigned short* weff = h1 + (size_t)B_ * KT_;           // [24,25.5M)
    unsigned short* w1b  = weff + (size_t)L_ * KT_;         // [25.5,26M)
    unsigned short* w2b  = w1b + (size_t)L_ * L_;           // [26,26.5M): till mgemm2
    unsigned short* lnx  = (unsigned short*)(out3);         // 8 MB in out3: till mgemm1
    unsigned short* m1   = (unsigned short*)d_out;          // 8 MB [0,8M): after h1 dead

    // 1) fused conv1+GELU -> h1 and LayerNorm -> lnx
    k_pre<<<B_, 256, 0, stream>>>(x, c1w, c1b, lg, lb, h1, lnx);
    // 2) weights -> bf16 + twiddle tables
    k_prep<<<L_ * L_ / 256, 256, 0, stream>>>(c3w, w1, w2, weff, w1b, w2b,
                                              tabd, tab, tab32);
    // 3) trend GEMM -> out2
    k_mgemm<0, KT_><<<dim3(64, 8), 256, 0, stream>>>(h1, weff, c3b, 0.875f, nullptr, out2);
    // 4) MLP1: GELU(lnx @ w1^T + b1) -> m1 (bf16; h1 now dead)
    k_mgemm<1, 512><<<dim3(64, 8), 256, 0, stream>>>(lnx, w1b, b1, 1.0f, nullptr, m1);
    // 5) MLP2: m1 @ w2^T + b2 + x -> out3 (lnx dead)
    k_mgemm<2, 512><<<dim3(64, 8), 256, 0, stream>>>(m1, w2b, b2, 1.0f, x, out3);
    // 6) season (4 rows/block) -> out1, zero -> out0 (all scratch dead)
    k_season<<<B_ / 4, 256, 0, stream>>>(x, tabd, tab, tab32, out1, out);
}

// Round 13
// 118.033 us; speedup vs baseline: 3.5623x; 1.0587x over previous
//
#include <hip/hip_runtime.h>
#include <hip/hip_bf16.h>
#include <math.h>

#define B_ 8192
#define L_ 512
#define BL_ (B_ * L_)
#define KT_ 1536

using bf16x8 = __attribute__((ext_vector_type(8))) short;
using f32x4  = __attribute__((ext_vector_type(4))) float;

__device__ __forceinline__ float gelu_f(float v) {
    return 0.5f * v * (1.0f + erff(v * 0.70710678118654752f));
}
__device__ __forceinline__ float bf2f(unsigned short u) {
    return __uint_as_float(((unsigned int)u) << 16);
}
__device__ __forceinline__ unsigned short f2bf(float f) {
    unsigned int x = __float_as_uint(f);
    x += 0x7fffu + ((x >> 16) & 1u);   // RNE
    return (unsigned short)(x >> 16);
}
__device__ __forceinline__ void gload16(const void* g, void* l) {
    __builtin_amdgcn_global_load_lds(
        (const __attribute__((address_space(1))) unsigned int*)g,
        (__attribute__((address_space(3))) unsigned int*)l, 16, 0, 0);
}

// fused conv1(1->3ch,k=3,pad1)+GELU -> h1 bf16 [b][c][i]  AND  LayerNorm -> lnx bf16
__global__ __launch_bounds__(256) void k_pre(const float* __restrict__ x,
        const float* __restrict__ c1w, const float* __restrict__ c1b,
        const float* __restrict__ lg, const float* __restrict__ lbias,
        unsigned short* __restrict__ h1, unsigned short* __restrict__ lnx) {
    __shared__ float xs[512];
    __shared__ float red[8];
    const int tid = threadIdx.x;
    const long b = blockIdx.x;
    const float* xr = x + (b << 9);
    float x0 = xr[tid], x1 = xr[tid + 256];
    xs[tid] = x0; xs[tid + 256] = x1;
    float s = x0 + x1, ss = x0 * x0 + x1 * x1;
#pragma unroll
    for (int off = 32; off > 0; off >>= 1) {
        s += __shfl_xor(s, off);
        ss += __shfl_xor(ss, off);
    }
    if ((tid & 63) == 0) { red[tid >> 6] = s; red[4 + (tid >> 6)] = ss; }
    __syncthreads();
    s  = red[0] + red[1] + red[2] + red[3];
    ss = red[4] + red[5] + red[6] + red[7];
    const float mu = s * (1.f / 512.f);
    const float rs = rsqrtf(ss * (1.f / 512.f) - mu * mu + 1e-5f);
    float w[9], cb[3];
#pragma unroll
    for (int j = 0; j < 9; ++j) w[j] = c1w[j];
#pragma unroll
    for (int j = 0; j < 3; ++j) cb[j] = c1b[j];
#pragma unroll
    for (int half = 0; half < 2; ++half) {
        const int i = tid + (half << 8);
        const float xm = i ? xs[i - 1] : 0.f;
        const float xc = xs[i];
        const float xp = (i != 511) ? xs[i + 1] : 0.f;
        unsigned short* hb = h1 + b * KT_ + i;
#pragma unroll
        for (int c = 0; c < 3; ++c) {
            float v = w[c * 3] * xm + w[c * 3 + 1] * xc + w[c * 3 + 2] * xp + cb[c];
            hb[(long)c << 9] = f2bf(gelu_f(v));
        }
        lnx[(b << 9) + i] = f2bf(fmaf((xc - mu) * rs, lg[i], lbias[i]));
    }
}

// weight prep: Weff bf16 [512][1536] (collapsed conv3+poly), w1/w2 -> bf16 [N][K]
// + twiddle tables (blocks 0-1): tabd(512 double2), tab(512 float2), tab32(32 float2)
__global__ __launch_bounds__(256) void k_prep(const float* __restrict__ c3w,
        const float* __restrict__ w1, const float* __restrict__ w2,
        unsigned short* __restrict__ weff, unsigned short* __restrict__ w1b,
        unsigned short* __restrict__ w2b,
        double2* __restrict__ tabd, float2* __restrict__ tab,
        float2* __restrict__ tab32) {
    int idx = blockIdx.x * 256 + threadIdx.x;      // 512*512
    if (idx < 512) {
        double sv, cv;
        sincos((double)idx * (3.14159265358979323846 / 256.0), &sv, &cv);
        tabd[idx] = make_double2(cv, sv);
        tab[idx] = make_float2((float)cv, (float)sv);
        if ((idx & 15) == 0) tab32[idx >> 4] = make_float2((float)cv, (float)sv);
    }
    int o = idx >> 9, i = idx & 511;
    const float* t = c3w + (size_t)idx * 3;
    float t0 = t[0], t1 = t[1], t2 = t[2];
    size_t base = (size_t)o * KT_ + i;
    weff[base]        = f2bf(0.25f * t0 + 0.5f * t1);
    weff[base + 512]  = f2bf(0.125f * t0 + 0.25f * t1 + 0.5f * t2);
    weff[base + 1024] = f2bf(0.125f * t1 + 0.25f * t2);
    w1b[idx] = f2bf(w1[idx]);
    w2b[idx] = f2bf(w2[idx]);
}

// MFMA GEMM: C[M,N] = A[M,K](bf16) * W[N,K](bf16)^T + sbias*bias
// BM=128 BN=64 BK=64, 4 waves, wave tile 64x32 (4x2 frags 16x16x32, 2 k-substeps)
// LDS [*][64] (128B rows): slot-XOR swizzle slot^=(row&7); source pre-swizzled,
// dest linear (= base + tid*16), read swizzled (rule #21).
template<int EMODE, int KD>
__global__ __launch_bounds__(256) void k_mgemm(
        const unsigned short* __restrict__ A, const unsigned short* __restrict__ W,
        const float* __restrict__ bias, float sbias,
        const float* __restrict__ xres, void* __restrict__ Cp) {
    __shared__ short As[128][64];
    __shared__ short Bs[64][64];
    const int tid = threadIdx.x;
    const int lane = tid & 63;
    const int wid = tid >> 6;
    const int m0 = blockIdx.x << 7;
    const int n0 = blockIdx.y << 6;
    const int wm = (wid & 1) << 6;
    const int wn = (wid >> 1) << 5;
    f32x4 acc[4][2] = {};

    const int srow = tid >> 3;          // 0..31 per segment
    const int schunk = tid & 7;         // 16B chunk within 64-col row
    const unsigned short* Ab = A + (size_t)m0 * KD;
    const unsigned short* Wb = W + (size_t)n0 * KD;
    const int frow = lane & 15;
    const int fsw = frow & 7;
    const int s0 = lane >> 4;           // k-subslot 0..3

    for (int k0 = 0; k0 < KD; k0 += 64) {
        __syncthreads();
#pragma unroll
        for (int seg = 0; seg < 4; ++seg) {
            const int r = (seg << 5) + srow;
            const int c = (schunk ^ (r & 7)) << 3;
            gload16(Ab + (size_t)r * KD + k0 + c, &As[r][schunk << 3]);
        }
#pragma unroll
        for (int seg = 0; seg < 2; ++seg) {
            const int r = (seg << 5) + srow;
            const int c = (schunk ^ (r & 7)) << 3;
            gload16(Wb + (size_t)r * KD + k0 + c, &Bs[r][schunk << 3]);
        }
        __syncthreads();
#pragma unroll
        for (int kk = 0; kk < 2; ++kk) {
            bf16x8 af[4], bfr[2];
            const int sl = (kk << 2) + s0;
#pragma unroll
            for (int m = 0; m < 4; ++m)
                af[m] = *(const bf16x8*)&As[wm + (m << 4) + frow][(sl ^ fsw) << 3];
#pragma unroll
            for (int n = 0; n < 2; ++n)
                bfr[n] = *(const bf16x8*)&Bs[wn + (n << 4) + frow][(sl ^ fsw) << 3];
#pragma unroll
            for (int m = 0; m < 4; ++m)
#pragma unroll
                for (int n = 0; n < 2; ++n)
                    acc[m][n] = __builtin_amdgcn_mfma_f32_16x16x32_bf16(af[m], bfr[n], acc[m][n], 0, 0, 0);
        }
    }

    const int col0 = n0 + wn + (lane & 15);
    const int rbase = m0 + wm + ((lane >> 4) << 2);
#pragma unroll
    for (int n = 0; n < 2; ++n) {
        const int col = col0 + (n << 4);
        const float bz = sbias * bias[col];
#pragma unroll
        for (int m = 0; m < 4; ++m) {
#pragma unroll
            for (int r = 0; r < 4; ++r) {
                const size_t row = rbase + (m << 4) + r;
                float v = acc[m][n][r] + bz;
                if (EMODE == 0) {
                    ((float*)Cp)[row * 512 + col] = v;
                } else if (EMODE == 1) {
                    ((unsigned short*)Cp)[row * 512 + col] = f2bf(gelu_f(v));
                } else {
                    ((float*)Cp)[row * 512 + col] = v + xres[row * 512 + col];
                }
            }
        }
    }
}

// season v5 (restored): 2 rows per block, strength-reduced twiddle indices.
// Per-bin arithmetic order identical to v1-v4 -> bit-identical output.
__global__ __launch_bounds__(256) void k_season(const float* __restrict__ x,
        const double2* __restrict__ gtabd, const float2* __restrict__ gtab,
        const float2* __restrict__ gtab32,
        float* __restrict__ out1, float* __restrict__ out0) {
    __shared__ float2 xp[2][256];   // p = 8*t1 + t0 -> (x[16t1+t0], x[16t1+t0+8])
    __shared__ float2 tab[512];     // synthesis twiddles (linear)
    __shared__ float2 Ys[2][512];   // [row][t0*32+rr]
    __shared__ unsigned long long wkey[2][4][5];
    __shared__ float2 wval[2][4][5];

    const int tid = threadIdx.x;
    const int w = tid >> 6, l = tid & 63;
    const long b = (long)blockIdx.x << 1;              // rows b, b+1
    const float* xr0 = x + (b << 9);
    const float* xr1 = xr0 + 512;

    // staging (one barrier)
    {
        const int t1s = tid >> 3, t0s = tid & 7;
        const int g = (t1s << 4) + t0s;
        xp[0][tid] = make_float2(xr0[g], xr0[g + 8]);
        xp[1][tid] = make_float2(xr1[g], xr1[g + 8]);
        tab[tid] = gtab[tid];
        tab[tid + 256] = gtab[tid + 256];
    }
    __syncthreads();                                   // barrier 1

    // stage 1: lane computes Y[t0][rr], Y[t0+8][rr] for both rows
    const int rr = (w << 3) + (l & 7);
    const int t0 = l >> 3;                             // 0..7
    float ra0 = 0.f, ia0 = 0.f, rb0 = 0.f, ib0 = 0.f;  // row0
    float ra1 = 0.f, ia1 = 0.f, rb1 = 0.f, ib1 = 0.f;  // row1
    int e32 = 0;
#pragma unroll
    for (int t1 = 0; t1 < 32; ++t1) {
        float2 wt = gtab32[e32];                       // (rr*t1)&31, L1-resident
        e32 = (e32 + rr) & 31;
        float2 v0 = xp[0][(t1 << 3) + t0];
        float2 v1 = xp[1][(t1 << 3) + t0];
        ra0 = fmaf(v0.x, wt.x, ra0); ia0 = fmaf(v0.x, wt.y, ia0);
        rb0 = fmaf(v0.y, wt.x, rb0); ib0 = fmaf(v0.y, wt.y, ib0);
        ra1 = fmaf(v1.x, wt.x, ra1); ia1 = fmaf(v1.x, wt.y, ia1);
        rb1 = fmaf(v1.y, wt.x, rb1); ib1 = fmaf(v1.y, wt.y, ib1);
    }
    // same-wave write->read (no barrier needed)
    Ys[0][(t0 << 5) + rr] = make_float2(ra0, -ia0);
    Ys[0][((t0 + 8) << 5) + rr] = make_float2(rb0, -ib0);
    Ys[1][(t0 << 5) + rr] = make_float2(ra1, -ia1);
    Ys[1][((t0 + 8) << 5) + rr] = make_float2(rb1, -ib1);

    // stage 2 (double): lane handles bin k for both rows
    const int k = ((l >> 3) << 5) + rr;                // 0..255, k=0 invalid
    double xre0 = 0.0, xim0 = 0.0, xre1 = 0.0, xim1 = 0.0;
    int e = 0;
#pragma unroll
    for (int t0i = 0; t0i < 16; ++t0i) {
        float2 y0 = Ys[0][(t0i << 5) + rr];
        float2 y1 = Ys[1][(t0i << 5) + rr];
        double2 wt = gtabd[e];                         // (k*t0i)&511
        e = (e + k) & 511;
        xre0 += (double)y0.x * wt.x + (double)y0.y * wt.y;
        xim0 += (double)y0.y * wt.x - (double)y0.x * wt.y;
        xre1 += (double)y1.x * wt.x + (double)y1.y * wt.y;
        xim1 += (double)y1.y * wt.x - (double)y1.x * wt.y;
    }

    // packed keys: mag top-52 bits | (4095-k) -> tie breaks to lower k
    unsigned long long key0 = 0, key1 = 0;
    if (k != 0) {
        double m0 = xre0 * xre0 + xim0 * xim0;
        double m1 = xre1 * xre1 + xim1 * xim1;
        key0 = (__double_as_longlong(m0) & ~0xFFFull) | (unsigned long long)(4095 - k);
        key1 = (__double_as_longlong(m1) & ~0xFFFull) | (unsigned long long)(4095 - k);
    }
    const float fre0 = (float)xre0, fim0 = (float)xim0;
    const float fre1 = (float)xre1, fim1 = (float)xim1;

    // wave-local top-5, both rows interleaved (no barriers)
    for (int rnd = 0; rnd < 5; ++rnd) {
        unsigned long long rk0 = key0, rk1 = key1;
#pragma unroll
        for (int off = 32; off > 0; off >>= 1) {
            unsigned long long o0 = __shfl_xor(rk0, off);
            unsigned long long o1 = __shfl_xor(rk1, off);
            rk0 = (o0 > rk0) ? o0 : rk0;
            rk1 = (o1 > rk1) ? o1 : rk1;
        }
        if (key0 == rk0 && rk0 != 0ull) {
            wkey[0][w][rnd] = rk0; wval[0][w][rnd] = make_float2(fre0, fim0); key0 = 0;
        }
        if (key1 == rk1 && rk1 != 0ull) {
            wkey[1][w][rnd] = rk1; wval[1][w][rnd] = make_float2(fre1, fim1); key1 = 0;
        }
    }
    __syncthreads();                                   // barrier 2

    // per row: merge 4 sorted lists of 5, then synthesis (+ zero out0)
#pragma unroll
    for (int row = 0; row < 2; ++row) {
        float4 sel[5];
        int h0 = 0, h1 = 0, h2 = 0, h3 = 0;
#pragma unroll
        for (int rnd = 0; rnd < 5; ++rnd) {
            unsigned long long c0 = wkey[row][0][h0], c1 = wkey[row][1][h1];
            unsigned long long c2 = wkey[row][2][h2], c3 = wkey[row][3][h3];
            unsigned long long bk = c0; int bw = 0;
            if (c1 > bk) { bk = c1; bw = 1; }
            if (c2 > bk) { bk = c2; bw = 2; }
            if (c3 > bk) { bk = c3; bw = 3; }
            const int hs = (bw == 0) ? h0 : (bw == 1) ? h1 : (bw == 2) ? h2 : h3;
            float2 v = wval[row][bw][hs];
            h0 += (bw == 0); h1 += (bw == 1); h2 += (bw == 2); h3 += (bw == 3);
            const int kk = 4095 - (int)(bk & 0xFFFull);
            sel[rnd] = make_float4((float)kk, v.x, v.y, 0.f);
        }
        const long ro = ((b + row) << 9);
#pragma unroll
        for (int half = 0; half < 2; ++half) {
            int t = tid + (half << 8);
            float acc = 0.f;
#pragma unroll
            for (int j = 0; j < 5; ++j) {
                float4 sj = sel[j];
                int kj = (int)sj.x;
                float2 wt = tab[(kj * t) & 511];
                acc += sj.y * wt.x - sj.z * wt.y;
            }
            out1[ro + t] = 2.f * acc;
            out0[ro + t] = 0.f;
        }
    }
}

extern "C" void kernel_launch(void* const* d_in, const int* in_sizes, int n_in,
                              void* d_out, int out_size, void* d_ws, size_t ws_size,
                              hipStream_t stream) {
    const float* x   = (const float*)d_in[0];
    const float* c1w = (const float*)d_in[1];
    const float* c1b = (const float*)d_in[2];
    const float* c3w = (const float*)d_in[3];
    const float* c3b = (const float*)d_in[4];
    const float* w1  = (const float*)d_in[5];
    const float* b1  = (const float*)d_in[6];
    const float* w2  = (const float*)d_in[7];
    const float* b2  = (const float*)d_in[8];
    const float* lg  = (const float*)d_in[9];
    const float* lb  = (const float*)d_in[10];

    float* out  = (float*)d_out;
    float* out1 = out + (long)BL_;          // season
    float* out2 = out + 2L * BL_;           // trend
    float* out3 = out + 3L * BL_;           // e

    // d_ws: twiddle tables (12.5 KB)
    double2* tabd = (double2*)d_ws;
    float2* tab   = (float2*)((char*)d_ws + 8192);
    float2* tab32 = (float2*)((char*)d_ws + 12288);

    // scratch in d_out (lifetimes ordered by the stream):
    unsigned short* h1   = (unsigned short*)d_out;          // 24 MB [0,24M): till trend GEMM
    unsigned short* weff = h1 + (size_t)B_ * KT_;           // [24,25.5M)
    unsigned short* w1b  = weff + (size_t)L_ * KT_;         // [25.5,26M)
    unsigned short* w2b  = w1b + (size_t)L_ * L_;           // [26,26.5M): till mgemm2
    unsigned short* lnx  = (unsigned short*)(out3);         // 8 MB in out3: till mgemm1
    unsigned short* m1   = (unsigned short*)d_out;          // 8 MB [0,8M): after h1 dead

    // 1) fused conv1+GELU -> h1 and LayerNorm -> lnx
    k_pre<<<B_, 256, 0, stream>>>(x, c1w, c1b, lg, lb, h1, lnx);
    // 2) weights -> bf16 + twiddle tables
    k_prep<<<L_ * L_ / 256, 256, 0, stream>>>(c3w, w1, w2, weff, w1b, w2b,
                                              tabd, tab, tab32);
    // 3) trend GEMM -> out2
    k_mgemm<0, KT_><<<dim3(64, 8), 256, 0, stream>>>(h1, weff, c3b, 0.875f, nullptr, out2);
    // 4) MLP1: GELU(lnx @ w1^T + b1) -> m1 (bf16; h1 now dead)
    k_mgemm<1, 512><<<dim3(64, 8), 256, 0, stream>>>(lnx, w1b, b1, 1.0f, nullptr, m1);
    // 5) MLP2: m1 @ w2^T + b2 + x -> out3 (lnx dead)
    k_mgemm<2, 512><<<dim3(64, 8), 256, 0, stream>>>(m1, w2b, b2, 1.0f, x, out3);
    // 6) season (2 rows/block) -> out1, zero -> out0 (all scratch dead)
    k_season<<<B_ / 2, 256, 0, stream>>>(x, tabd, tab, tab32, out1, out);
}